// Round 18
// baseline (2293.085 us; speedup 1.0000x reference)
//
#include <hip/hip_runtime.h>

typedef __attribute__((ext_vector_type(4))) float  f32x4;
typedef __attribute__((ext_vector_type(8))) short  bf16x8;

#define TAU 2.0e-3f
#define CAP 8192

__device__ __forceinline__ short f2bf(float f) {
    unsigned u = __builtin_bit_cast(unsigned, f);
    unsigned r = (u + 0x7FFFu + ((u >> 16) & 1u)) >> 16;
    return (short)r;
}
__device__ __forceinline__ float bf2f(unsigned short us) {
    return __builtin_bit_cast(float, (unsigned)us << 16);
}

// ---------- f32 -> bf16 elementwise convert (8 elems/thread) ----------
__global__ __launch_bounds__(256)
void cvt_bf16(const float* __restrict__ in, short* __restrict__ out, long n8)
{
    long i = (long)blockIdx.x * 256 + threadIdx.x;
    if (i >= n8) return;
    const float4* p = (const float4*)(in + i * 8);
    float4 a = p[0], b = p[1];
    bf16x8 v;
    v[0] = f2bf(a.x); v[1] = f2bf(a.y); v[2] = f2bf(a.z); v[3] = f2bf(a.w);
    v[4] = f2bf(b.x); v[5] = f2bf(b.y); v[6] = f2bf(b.z); v[7] = f2bf(b.w);
    *(bf16x8*)(out + i * 8) = v;
}

// ---------- bf16 MFMA fast GEMM (proven decoder structure), 128x128x64 ----------
// A bf16 [M][K], Bt bf16 [N][K].
// EPI 0: O1 bf16 = relu(acc + P1[col])                      (GEMM1 -> hb)
// EPI 1: O1 f32 = relu(acc + P1[col]); O2 bf16 = same      (GEMM2 -> z, zb)
// EPI 2: O1 f32 = P1[col] - 2*acc                           (s-GEMM, P1 = e2v)
template<int EPI>
__global__ __launch_bounds__(256)
void gemm_bf16f(const short* __restrict__ A, const short* __restrict__ Bt,
                const float* __restrict__ P1, void* __restrict__ O1,
                void* __restrict__ O2, int N, int K)
{
    __shared__ short As[128][72];
    __shared__ short Bs[128][72];
    const int tid = threadIdx.x;
    const int lane = tid & 63;
    const int wave = tid >> 6;
    const int wm = (wave >> 1) * 64;
    const int wn = (wave & 1) * 64;
    const size_t bm = (size_t)blockIdx.x * 128;
    const size_t bn = (size_t)blockIdx.y * 128;
    const int fr = lane & 15;
    const int fk8 = (lane >> 4) * 8;

    f32x4 acc[4][4];
#pragma unroll
    for (int m = 0; m < 4; ++m)
#pragma unroll
        for (int n = 0; n < 4; ++n) acc[m][n] = (f32x4)0.f;

    const int sr = tid >> 1;
    const int sk = (tid & 1) * 32;

    for (int k0 = 0; k0 < K; k0 += 64) {
        const uint4* ap4 = (const uint4*)(A + (bm + sr) * (size_t)K + k0 + sk);
        const uint4* bp4 = (const uint4*)(Bt + (bn + sr) * (size_t)K + k0 + sk);
        uint4 av[4], bv[4];
#pragma unroll
        for (int j = 0; j < 4; ++j) { av[j] = ap4[j]; bv[j] = bp4[j]; }
        __syncthreads();
#pragma unroll
        for (int j = 0; j < 4; ++j) {
            *(uint4*)&As[sr][sk + 8 * j] = av[j];
            *(uint4*)&Bs[sr][sk + 8 * j] = bv[j];
        }
        __syncthreads();
#pragma unroll
        for (int kk = 0; kk < 2; ++kk) {
            bf16x8 a[4], b[4];
#pragma unroll
            for (int m = 0; m < 4; ++m)
                a[m] = *(const bf16x8*)&As[wm + m * 16 + fr][kk * 32 + fk8];
#pragma unroll
            for (int n = 0; n < 4; ++n)
                b[n] = *(const bf16x8*)&Bs[wn + n * 16 + fr][kk * 32 + fk8];
#pragma unroll
            for (int m = 0; m < 4; ++m)
#pragma unroll
                for (int n = 0; n < 4; ++n)
                    acc[m][n] = __builtin_amdgcn_mfma_f32_16x16x32_bf16(a[m], b[n], acc[m][n], 0, 0, 0);
        }
    }
#pragma unroll
    for (int m = 0; m < 4; ++m)
#pragma unroll
        for (int n = 0; n < 4; ++n)
#pragma unroll
            for (int i = 0; i < 4; ++i) {
                const size_t row = bm + wm + m * 16 + (lane >> 4) * 4 + i;
                const int col = (int)bn + wn + n * 16 + fr;
                float p1 = P1[col];
                if (EPI == 0) {
                    float v = fmaxf(acc[m][n][i] + p1, 0.f);
                    ((short*)O1)[row * (size_t)N + col] = f2bf(v);
                } else if (EPI == 1) {
                    float v = fmaxf(acc[m][n][i] + p1, 0.f);
                    ((float*)O1)[row * (size_t)N + col] = v;
                    ((short*)O2)[row * (size_t)N + col] = f2bf(v);
                } else {
                    ((float*)O1)[row * (size_t)N + col] = fmaf(-2.f, acc[m][n][i], p1);
                }
            }
}

// ---------- bit-exact f64 GEMM (r13/r15-proven), chunked early-exit ----------
__global__ __launch_bounds__(256, 4)
void gemm_f64(const float* __restrict__ A, const float* __restrict__ B,
              const float* __restrict__ P1, const float* __restrict__ P2,
              float* __restrict__ C, int lda, int ldb, int ldc, int K,
              const int* __restrict__ cnt, int base, int mult)
{
    __shared__ double As[16][128];
    __shared__ double Ws[16][68];
    const int tid = threadIdx.x;
    const size_t bm = (size_t)blockIdx.x * 128;
    {
        int nn = *cnt - base;
        nn = nn < 0 ? 0 : (nn > CAP ? CAP : nn);
        if ((int)bm >= nn * mult) return;
    }
    const size_t bn = (size_t)blockIdx.y * 64;
    const int ty = tid >> 4, tx = tid & 15;

    double acc[8][4];
#pragma unroll
    for (int i = 0; i < 8; ++i)
#pragma unroll
        for (int j = 0; j < 4; ++j) acc[i][j] = 0.0;

    const int ar = tid >> 1, ak = (tid & 1) * 8;
    const int wr = tid >> 4;
    const int wq = tx * 4;
    const int qh = tx >> 3;
    const int col0 = wq + 2 * qh;
    const int col1 = wq + 2 - 2 * qh;

    const float* apBase = A + (bm + ar) * (size_t)lda + ak;
    const float* wpBase = B + (size_t)wr * ldb + bn + wq;

    float4 av0 = *(const float4*)(apBase);
    float4 av1 = *(const float4*)(apBase + 4);
    float4 wv  = *(const float4*)(wpBase);

    for (int k0 = 0; k0 < K; k0 += 16) {
        __syncthreads();
        As[ak + 0][ar] = (double)av0.x;  As[ak + 1][ar] = (double)av0.y;
        As[ak + 2][ar] = (double)av0.z;  As[ak + 3][ar] = (double)av0.w;
        As[ak + 4][ar] = (double)av1.x;  As[ak + 5][ar] = (double)av1.y;
        As[ak + 6][ar] = (double)av1.z;  As[ak + 7][ar] = (double)av1.w;
        *(double2*)&Ws[wr][col0] = make_double2((double)wv.x, (double)wv.y);
        *(double2*)&Ws[wr][col1] = make_double2((double)wv.z, (double)wv.w);
        __syncthreads();
        if (k0 + 16 < K) {
            av0 = *(const float4*)(apBase + k0 + 16);
            av1 = *(const float4*)(apBase + k0 + 20);
            wv  = *(const float4*)(wpBase + (size_t)(k0 + 16) * ldb);
        }
#pragma unroll
        for (int kk = 0; kk < 16; ++kk) {
            const double* arp = &As[kk][ty * 8];
            double a[8];
#pragma unroll
            for (int t = 0; t < 8; ++t) a[t] = arp[t];
            double2 b01 = *(const double2*)&Ws[kk][col0];
            double2 b23 = *(const double2*)&Ws[kk][col1];
            double b[4] = {b01.x, b01.y, b23.x, b23.y};
#pragma unroll
            for (int i = 0; i < 8; ++i)
#pragma unroll
                for (int j = 0; j < 4; ++j)
                    acc[i][j] = fma(a[i], b[j], acc[i][j]);
        }
    }
#pragma unroll
    for (int i = 0; i < 8; ++i) {
        const size_t row = bm + ty * 8 + i;
        float o[4];
        if (P2 == nullptr) {
#pragma unroll
            for (int j = 0; j < 4; ++j) {
                float mm = (float)acc[i][j];
                float v  = __fadd_rn(mm, P1[bn + tx * 4 + j]);
                o[j] = fmaxf(v, 0.f);
            }
        } else {
            const float z2 = P1[row];
#pragma unroll
            for (int j = 0; j < 4; ++j) {
                float m32  = (float)acc[i][j];
                float twom = __fmul_rn(2.0f, m32);
                float t    = __fsub_rn(z2, twom);
                o[j] = __fadd_rn(t, P2[bn + tx * 4 + j]);
            }
        }
        *(float4*)(C + row * (size_t)ldc + bn + tx * 4) = make_float4(o[0], o[1], o[2], o[3]);
    }
}

// ---------- E transpose ----------
__global__ __launch_bounds__(256)
void transpose_f32(const float* __restrict__ in, float* __restrict__ out)
{
    int i = blockIdx.x * 256 + threadIdx.x;
    int r = i & 255, k = i >> 8;
    out[i] = in[r * 512 + k];
}

// ---------- numpy-pairwise f32 row sum-of-squares (bit-exact) ----------
__device__ __forceinline__ float np_pairwise_sq_512(const float* __restrict__ p)
{
    float b[4];
#pragma unroll
    for (int blk = 0; blk < 4; ++blk) {
        const float* q = p + blk * 128;
        float r[8];
#pragma unroll
        for (int j = 0; j < 8; ++j) { float v = q[j]; r[j] = __fmul_rn(v, v); }
        for (int t = 1; t < 16; ++t)
#pragma unroll
            for (int j = 0; j < 8; ++j) {
                float v = q[8 * t + j];
                r[j] = __fadd_rn(r[j], __fmul_rn(v, v));
            }
        float s01 = __fadd_rn(r[0], r[1]), s23 = __fadd_rn(r[2], r[3]);
        float s45 = __fadd_rn(r[4], r[5]), s67 = __fadd_rn(r[6], r[7]);
        b[blk] = __fadd_rn(__fadd_rn(s01, s23), __fadd_rn(s45, s67));
    }
    return __fadd_rn(__fadd_rn(b[0], b[1]), __fadd_rn(b[2], b[3]));
}

__global__ __launch_bounds__(256)
void rowsq_np(const float* __restrict__ a, float* __restrict__ out, int nrows)
{
    int r = blockIdx.x * 256 + threadIdx.x;
    if (r >= nrows) return;
    out[r] = np_pairwise_sq_512(a + (size_t)r * 512);
}

__global__ __launch_bounds__(256)
void rowsq_c(const float* __restrict__ zc, float* __restrict__ z2c,
             const int* __restrict__ cnt, int base)
{
    int r = blockIdx.x * 256 + threadIdx.x;
    int nn = *cnt - base;
    nn = nn < 0 ? 0 : (nn > CAP ? CAP : nn);
    if (r >= nn) return;
    z2c[r] = np_pairwise_sq_512(zc + (size_t)r * 512);
}

__global__ void zero_counter(int* __restrict__ c) { if (threadIdx.x == 0) *c = 0; }

// ---------- margin-gated argmin -> qb only ----------
__global__ __launch_bounds__(256)
void argmin_margin(const float* __restrict__ s, const float* __restrict__ E,
                   short* __restrict__ qb, int* __restrict__ slist, int* __restrict__ counter)
{
    const int wave = threadIdx.x >> 6;
    const int lane = threadIdx.x & 63;
    const size_t row = (size_t)blockIdx.x * 4 + wave;
    const float* srow = s + row * 256;
    float m1 = 3.0e38f, m2 = 3.0e38f;
    int i1 = 0;
#pragma unroll
    for (int t = 0; t < 4; ++t) {
        int i = lane + t * 64;
        float v = srow[i];
        if (v < m1 || (v == m1 && i < i1)) { m2 = m1; m1 = v; i1 = i; }
        else m2 = fminf(m2, v);
    }
#pragma unroll
    for (int mm = 32; mm; mm >>= 1) {
        float o1 = __shfl_xor(m1, mm);
        int   oi = __shfl_xor(i1, mm);
        float o2 = __shfl_xor(m2, mm);
        if (o1 < m1 || (o1 == m1 && oi < i1)) { m2 = fminf(m1, o2); m1 = o1; i1 = oi; }
        else m2 = fminf(m2, o1);
    }
    if (m2 - m1 > TAU) {
        const float4* er = (const float4*)(E + (size_t)i1 * 512);
        float4 e0 = er[lane * 2], e1 = er[lane * 2 + 1];
        bf16x8 bv8;
        bv8[0] = f2bf(e0.x); bv8[1] = f2bf(e0.y); bv8[2] = f2bf(e0.z); bv8[3] = f2bf(e0.w);
        bv8[4] = f2bf(e1.x); bv8[5] = f2bf(e1.y); bv8[6] = f2bf(e1.z); bv8[7] = f2bf(e1.w);
        *(bf16x8*)&qb[row * 512 + lane * 8] = bv8;
    } else if (lane == 0) {
        int slot = atomicAdd(counter, 1);
        slist[slot] = (int)row;
    }
}

// ---------- gather suspect x rows -> compact xc ----------
__global__ __launch_bounds__(256)
void gather_xc(const float* __restrict__ x, const int* __restrict__ slist,
               const int* __restrict__ cnt, int base, float* __restrict__ xc)
{
    int b = blockIdx.x;
    if (base + b >= *cnt) return;
    int r = slist[base + b];
    const float4* src = (const float4*)(x + (size_t)(2 * r) * 1024);
    float4* dst = (float4*)(xc + (size_t)(2 * b) * 1024);
    dst[threadIdx.x]       = src[threadIdx.x];
    dst[threadIdx.x + 256] = src[threadIdx.x + 256];
}

// ---------- exact argmin over compacted d2 + scatter qb ----------
__global__ __launch_bounds__(256)
void argmin_scatter(const float* __restrict__ d2c, const float* __restrict__ E,
                    short* __restrict__ qb, const int* __restrict__ slist,
                    const int* __restrict__ cnt, int base)
{
    const int wave = threadIdx.x >> 6;
    const int lane = threadIdx.x & 63;
    const int b = blockIdx.x * 4 + wave;
    if (base + b >= *cnt) return;
    const int r = slist[base + b];
    const float* srow = d2c + (size_t)b * 256;
    float bv = srow[lane];
    int bi = lane;
#pragma unroll
    for (int t = 1; t < 4; ++t) {
        int i = lane + t * 64;
        float v = srow[i];
        if (v < bv) { bv = v; bi = i; }
    }
#pragma unroll
    for (int m = 32; m; m >>= 1) {
        float ov = __shfl_xor(bv, m);
        int oi = __shfl_xor(bi, m);
        if (ov < bv || (ov == bv && oi < bi)) { bv = ov; bi = oi; }
    }
    const float4* er = (const float4*)(E + (size_t)bi * 512);
    float4 e0 = er[lane * 2], e1 = er[lane * 2 + 1];
    bf16x8 bv8;
    bv8[0] = f2bf(e0.x); bv8[1] = f2bf(e0.y); bv8[2] = f2bf(e0.z); bv8[3] = f2bf(e0.w);
    bv8[4] = f2bf(e1.x); bv8[5] = f2bf(e1.y); bv8[6] = f2bf(e1.z); bv8[7] = f2bf(e1.w);
    *(bf16x8*)&qb[(size_t)r * 512 + lane * 8] = bv8;
}

// ---------- loss: z f32 vs qb bf16 ----------
__global__ __launch_bounds__(256)
void loss_partial(const float* __restrict__ z, const short* __restrict__ qb,
                  double* __restrict__ partials, long n4)
{
    const float4* z4 = (const float4*)z;
    double s = 0.0;
    for (long i = (long)blockIdx.x * 256 + threadIdx.x; i < n4; i += (long)gridDim.x * 256) {
        float4 a = z4[i];
        const unsigned short* qp = (const unsigned short*)(qb + i * 4);
        double dx = (double)a.x - (double)bf2f(qp[0]);
        double dy = (double)a.y - (double)bf2f(qp[1]);
        double dz = (double)a.z - (double)bf2f(qp[2]);
        double dw = (double)a.w - (double)bf2f(qp[3]);
        s += dx * dx + dy * dy + dz * dz + dw * dw;
    }
    __shared__ double red[256];
    red[threadIdx.x] = s;
    __syncthreads();
    for (int off = 128; off; off >>= 1) {
        if (threadIdx.x < off) red[threadIdx.x] += red[threadIdx.x + off];
        __syncthreads();
    }
    if (threadIdx.x == 0) partials[blockIdx.x] = red[0];
}

__global__ __launch_bounds__(256)
void loss_final(const double* __restrict__ partials, float* __restrict__ out)
{
    __shared__ double red[256];
    double s = 0.0;
    for (int i = threadIdx.x; i < 1024; i += 256) s += partials[i];
    red[threadIdx.x] = s;
    __syncthreads();
    for (int off = 128; off; off >>= 1) {
        if (threadIdx.x < off) red[threadIdx.x] += red[threadIdx.x + off];
        __syncthreads();
    }
    if (threadIdx.x == 0) out[0] = (float)(red[0] * (1.25 / 16777216.0));
}

// ---------- transpose f32 [K][N] -> bf16 [N][K] ----------
__global__ __launch_bounds__(256)
void transpose_bf16(const float* __restrict__ in, short* __restrict__ out,
                    int N, int kshift, long total)
{
    long i = (long)blockIdx.x * 256 + threadIdx.x;
    if (i >= total) return;
    int k = (int)(i & ((1 << kshift) - 1));
    int n = (int)(i >> kshift);
    out[i] = f2bf(in[(size_t)k * N + n]);
}

// ---------- decoder GEMM via bf16 MFMA (round-8 proven) ----------
template<bool RELU, bool OUTBF16>
__global__ __launch_bounds__(256)
void gemm_dec_bf16(const short* __restrict__ A, const short* __restrict__ Bt,
                   const float* __restrict__ bias, void* __restrict__ Cout,
                   int N, int K)
{
    __shared__ short As[128][72];
    __shared__ short Bs[128][72];
    const int tid = threadIdx.x;
    const int lane = tid & 63;
    const int wave = tid >> 6;
    const int wm = (wave >> 1) * 64;
    const int wn = (wave & 1) * 64;
    const size_t bm = (size_t)blockIdx.x * 128;
    const size_t bn = (size_t)blockIdx.y * 128;
    const int fr = lane & 15;
    const int fk8 = (lane >> 4) * 8;

    f32x4 acc[4][4];
#pragma unroll
    for (int m = 0; m < 4; ++m)
#pragma unroll
        for (int n = 0; n < 4; ++n) acc[m][n] = (f32x4)0.f;

    const int sr = tid >> 1;
    const int sk = (tid & 1) * 32;

    for (int k0 = 0; k0 < K; k0 += 64) {
        const uint4* ap4 = (const uint4*)(A + (bm + sr) * (size_t)K + k0 + sk);
        const uint4* bp4 = (const uint4*)(Bt + (bn + sr) * (size_t)K + k0 + sk);
        uint4 av[4], bv[4];
#pragma unroll
        for (int j = 0; j < 4; ++j) { av[j] = ap4[j]; bv[j] = bp4[j]; }
        __syncthreads();
#pragma unroll
        for (int j = 0; j < 4; ++j) {
            *(uint4*)&As[sr][sk + 8 * j] = av[j];
            *(uint4*)&Bs[sr][sk + 8 * j] = bv[j];
        }
        __syncthreads();
#pragma unroll
        for (int kk = 0; kk < 2; ++kk) {
            bf16x8 a[4], b[4];
#pragma unroll
            for (int m = 0; m < 4; ++m)
                a[m] = *(const bf16x8*)&As[wm + m * 16 + fr][kk * 32 + fk8];
#pragma unroll
            for (int n = 0; n < 4; ++n)
                b[n] = *(const bf16x8*)&Bs[wn + n * 16 + fr][kk * 32 + fk8];
#pragma unroll
            for (int m = 0; m < 4; ++m)
#pragma unroll
                for (int n = 0; n < 4; ++n)
                    acc[m][n] = __builtin_amdgcn_mfma_f32_16x16x32_bf16(a[m], b[n], acc[m][n], 0, 0, 0);
        }
    }
#pragma unroll
    for (int m = 0; m < 4; ++m)
#pragma unroll
        for (int n = 0; n < 4; ++n)
#pragma unroll
            for (int i = 0; i < 4; ++i) {
                const size_t row = bm + wm + m * 16 + (lane >> 4) * 4 + i;
                const int col = (int)bn + wn + n * 16 + fr;
                float v = acc[m][n][i] + bias[col];
                if (RELU) v = fmaxf(v, 0.f);
                if (OUTBF16) ((short*)Cout)[row * (size_t)N + col] = f2bf(v);
                else         ((float*)Cout)[row * (size_t)N + col] = v;
            }
}

extern "C" void kernel_launch(void* const* d_in, const int* in_sizes, int n_in,
                              void* d_out, int out_size, void* d_ws, size_t ws_size,
                              hipStream_t stream)
{
    const float* x   = (const float*)d_in[0];
    const float* W1  = (const float*)d_in[1];
    const float* b1  = (const float*)d_in[2];
    const float* W2  = (const float*)d_in[3];
    const float* b2  = (const float*)d_in[4];
    const float* E   = (const float*)d_in[5];
    const float* Wd1 = (const float*)d_in[6];
    const float* bd1 = (const float*)d_in[7];
    const float* Wd2 = (const float*)d_in[8];
    const float* bd2 = (const float*)d_in[9];
    float* out = (float*)d_out;

    float* ws = (float*)d_ws;
    // Phase-overlapped layout (liveness-checked):
    short*  xb    = (short*)ws;                   // [0, 33.5M) bf16 x; dead after GEMM1
    short*  W2bt  = (short*)ws;                   // [0, 65,536) after GEMM1
    short*  Eb    = (short*)(ws + 65536);         // [65,536, 131,072)
    float*  sbuf  = ws + 8388608;                 // [8.4M, 16.8M) s'; dead after argmin
    float*  xc    = ws;                           // [0, 16.8M) recompute (after argmin)
    short*  Wd1t  = (short*)ws;                   // [0, 65,536) decoder phase
    short*  Wd2t  = (short*)(ws + 65536);         // [65,536, 327,680)
    short*  qb    = (short*)(ws + 16777216);      // [16.8M, 33.5M)
    short*  W1bt  = (short*)(ws + 33554432);      // [33.5M, 33.8M); dead after GEMM1
    float*  z     = ws + 33554432;                // [33.5M, 50.3M) f32 (GEMM2 out)
    short*  hb    = (short*)(ws + 50331648);      // [50.3M, 67.1M); dead after GEMM2
    float*  hc    = ws + 50331648;                // [50.3M, 58.7M) recompute
    float*  zc    = ws + 58720256;                // [58.7M, 62.9M)
    float*  d2c   = ws + 62914560;                // [62.9M, 65.0M)
    short*  a1b   = (short*)(ws + 50331648);      // decoder phase (hb/hc/zc/d2c dead)
    short*  zb    = (short*)(ws + 67108864);      // [67.1M, 75.5M) bf16 z
    float*  Et    = ws + 75497472;                // [75.5M, +131,072)
    float*  e2v   = ws + 75628544;                // 256
    double* partials = (double*)(ws + 75628800);  // 1024 f64
    int*    slist   = (int*)(ws + 75630848);      // 32,768
    int*    counter = (int*)(ws + 75663616);      // 1
    float*  z2c   = ws + 75663680;                // 8,192  (end 75,671,872 < r17 max)

    dim3 blk(256);
    // convert inputs for fast bf16 path
    cvt_bf16<<<dim3(32768), blk, 0, stream>>>(x, xb, 8388608L);
    transpose_bf16<<<dim3(2048), blk, 0, stream>>>(W1, W1bt, 512, 10, 524288L);
    transpose_f32<<<dim3(512), blk, 0, stream>>>(E, Et);
    rowsq_np<<<dim3(1), blk, 0, stream>>>(E, e2v, 256);
    // fast path: bf16 MFMA GEMMs
    gemm_bf16f<0><<<dim3(512, 4), blk, 0, stream>>>(xb, W1bt, b1, hb, nullptr, 512, 1024);
    transpose_bf16<<<dim3(512), blk, 0, stream>>>(W2, W2bt, 256, 9, 131072L);   // xb dead
    cvt_bf16<<<dim3(64), blk, 0, stream>>>(E, Eb, 16384L);
    gemm_bf16f<1><<<dim3(512, 2), blk, 0, stream>>>(hb, W2bt, b2, z, zb, 256, 512);
    gemm_bf16f<2><<<dim3(256, 2), blk, 0, stream>>>(zb, Eb, e2v, sbuf, nullptr, 256, 512);
    // margin-gated argmin (TAU=2e-3; bf16-path comparison error bound ~5e-4)
    zero_counter<<<dim3(1), dim3(64), 0, stream>>>(counter);
    argmin_margin<<<dim3(8192), blk, 0, stream>>>(sbuf, E, qb, slist, counter);
    // bit-exact compacted-GEMM recompute, 4 chunks (beyond-n chunks are no-ops)
    for (int c = 0; c < 4; ++c) {
        const int base = c * CAP;
        gather_xc<<<dim3(CAP), blk, 0, stream>>>(x, slist, counter, base, xc);
        gemm_f64<<<dim3(128, 8), blk, 0, stream>>>(xc, W1, b1, nullptr, hc, 1024, 512, 512, 1024, counter, base, 2);
        gemm_f64<<<dim3(128, 4), blk, 0, stream>>>(hc, W2, b2, nullptr, zc, 512, 256, 256, 512, counter, base, 2);
        rowsq_c<<<dim3(32), blk, 0, stream>>>(zc, z2c, counter, base);
        gemm_f64<<<dim3(64, 4), blk, 0, stream>>>(zc, Et, z2c, e2v, d2c, 512, 256, 256, 512, counter, base, 1);
        argmin_scatter<<<dim3(2048), blk, 0, stream>>>(d2c, E, qb, slist, counter, base);
    }
    // vq_loss = 1.25 * mean((qb - z)^2)
    loss_partial<<<dim3(1024), blk, 0, stream>>>(z, qb, partials, 4194304L);
    loss_final<<<dim3(1), blk, 0, stream>>>(partials, out + (size_t)out_size - 1);
    // decoder weights (xc dead)
    transpose_bf16<<<dim3(512), blk, 0, stream>>>(Wd1, Wd1t, 512, 8, 131072L);
    transpose_bf16<<<dim3(2048), blk, 0, stream>>>(Wd2, Wd2t, 1024, 9, 524288L);
    // decoder (bf16 MFMA; zq == q in forward)
    gemm_dec_bf16<true,  true ><<<dim3(512, 4), blk, 0, stream>>>(qb,  Wd1t, bd1, a1b, 512, 256);
    gemm_dec_bf16<false, false><<<dim3(512, 8), blk, 0, stream>>>(a1b, Wd2t, bd2, out, 1024, 512);
}

// Round 19
// 2167.516 us; speedup vs baseline: 1.0579x; 1.0579x over previous
//
#include <hip/hip_runtime.h>

typedef __attribute__((ext_vector_type(4))) float  f32x4;
typedef __attribute__((ext_vector_type(8))) short  bf16x8;

#define TAU 2.0e-4f
#define CAP 8192

__device__ __forceinline__ short f2bf(float f) {
    unsigned u = __builtin_bit_cast(unsigned, f);
    unsigned r = (u + 0x7FFFu + ((u >> 16) & 1u)) >> 16;
    return (short)r;
}
__device__ __forceinline__ float bf2f(unsigned short us) {
    return __builtin_bit_cast(float, (unsigned)us << 16);
}

// ---------- fast f32 GEMM, 128x128x16 tile, 8x8 micro, prefetch (r17-proven) ----------
// EPI 0: C = relu(acc + P1[col])   (encoder)
// EPI 1: C = P1[col] - 2*acc       (VQ score s'; P1 = e2v; z2 cancels in argmin)
template<int EPI>
__global__ __launch_bounds__(256)
void gemm_f32t(const float* __restrict__ A, const float* __restrict__ B,
               const float* __restrict__ P1, float* __restrict__ C,
               int lda, int ldb, int ldc, int K)
{
    __shared__ float As[16][128];
    __shared__ float Ws[16][140];
    const int tid = threadIdx.x;
    const size_t bm = (size_t)blockIdx.x * 128;
    const size_t bn = (size_t)blockIdx.y * 128;
    const int ty = tid >> 4, tx = tid & 15;

    float acc[8][8];
#pragma unroll
    for (int i = 0; i < 8; ++i)
#pragma unroll
        for (int j = 0; j < 8; ++j) acc[i][j] = 0.f;

    const int ar = tid >> 1, ak = (tid & 1) * 8;
    const int wr = tid >> 4, wc = (tid & 15) * 8;
    const int wcs = wc + 4 * ((tid & 15) >> 2);
    const int bcs = tx * 8 + 4 * (tx >> 2);

    const float* apB = A + (bm + ar) * (size_t)lda + ak;
    const float* wpB = B + (size_t)wr * ldb + bn + wc;

    float4 av0 = *(const float4*)(apB);
    float4 av1 = *(const float4*)(apB + 4);
    float4 wv0 = *(const float4*)(wpB);
    float4 wv1 = *(const float4*)(wpB + 4);

    for (int k0 = 0; k0 < K; k0 += 16) {
        __syncthreads();
        As[ak + 0][ar] = av0.x;  As[ak + 1][ar] = av0.y;
        As[ak + 2][ar] = av0.z;  As[ak + 3][ar] = av0.w;
        As[ak + 4][ar] = av1.x;  As[ak + 5][ar] = av1.y;
        As[ak + 6][ar] = av1.z;  As[ak + 7][ar] = av1.w;
        *(float4*)&Ws[wr][wcs]     = wv0;
        *(float4*)&Ws[wr][wcs + 4] = wv1;
        __syncthreads();
        if (k0 + 16 < K) {
            av0 = *(const float4*)(apB + k0 + 16);
            av1 = *(const float4*)(apB + k0 + 20);
            wv0 = *(const float4*)(wpB + (size_t)(k0 + 16) * ldb);
            wv1 = *(const float4*)(wpB + (size_t)(k0 + 16) * ldb + 4);
        }
#pragma unroll
        for (int kk = 0; kk < 16; ++kk) {
            float4 a0 = *(const float4*)&As[kk][ty * 8];
            float4 a1 = *(const float4*)&As[kk][ty * 8 + 4];
            float4 w0 = *(const float4*)&Ws[kk][bcs];
            float4 w1 = *(const float4*)&Ws[kk][bcs + 4];
            float a[8] = {a0.x, a0.y, a0.z, a0.w, a1.x, a1.y, a1.z, a1.w};
            float w[8] = {w0.x, w0.y, w0.z, w0.w, w1.x, w1.y, w1.z, w1.w};
#pragma unroll
            for (int i = 0; i < 8; ++i)
#pragma unroll
                for (int j = 0; j < 8; ++j)
                    acc[i][j] = fmaf(a[i], w[j], acc[i][j]);
        }
    }
#pragma unroll
    for (int i = 0; i < 8; ++i) {
        const size_t row = bm + ty * 8 + i;
        float o[8];
#pragma unroll
        for (int j = 0; j < 8; ++j) {
            if (EPI == 0) o[j] = fmaxf(acc[i][j] + P1[bn + tx * 8 + j], 0.f);
            else          o[j] = fmaf(-2.f, acc[i][j], P1[bn + tx * 8 + j]);
        }
        float4* cp = (float4*)(C + row * (size_t)ldc + bn + tx * 8);
        cp[0] = make_float4(o[0], o[1], o[2], o[3]);
        cp[1] = make_float4(o[4], o[5], o[6], o[7]);
    }
}

// ---------- bit-exact f64 GEMM (r13/r15-proven), chunked early-exit ----------
__global__ __launch_bounds__(256, 4)
void gemm_f64(const float* __restrict__ A, const float* __restrict__ B,
              const float* __restrict__ P1, const float* __restrict__ P2,
              float* __restrict__ C, int lda, int ldb, int ldc, int K,
              const int* __restrict__ cnt, int base, int mult)
{
    __shared__ double As[16][128];
    __shared__ double Ws[16][68];
    const int tid = threadIdx.x;
    const size_t bm = (size_t)blockIdx.x * 128;
    {
        int nn = *cnt - base;
        nn = nn < 0 ? 0 : (nn > CAP ? CAP : nn);
        if ((int)bm >= nn * mult) return;
    }
    const size_t bn = (size_t)blockIdx.y * 64;
    const int ty = tid >> 4, tx = tid & 15;

    double acc[8][4];
#pragma unroll
    for (int i = 0; i < 8; ++i)
#pragma unroll
        for (int j = 0; j < 4; ++j) acc[i][j] = 0.0;

    const int ar = tid >> 1, ak = (tid & 1) * 8;
    const int wr = tid >> 4;
    const int wq = tx * 4;
    const int qh = tx >> 3;
    const int col0 = wq + 2 * qh;
    const int col1 = wq + 2 - 2 * qh;

    const float* apBase = A + (bm + ar) * (size_t)lda + ak;
    const float* wpBase = B + (size_t)wr * ldb + bn + wq;

    float4 av0 = *(const float4*)(apBase);
    float4 av1 = *(const float4*)(apBase + 4);
    float4 wv  = *(const float4*)(wpBase);

    for (int k0 = 0; k0 < K; k0 += 16) {
        __syncthreads();
        As[ak + 0][ar] = (double)av0.x;  As[ak + 1][ar] = (double)av0.y;
        As[ak + 2][ar] = (double)av0.z;  As[ak + 3][ar] = (double)av0.w;
        As[ak + 4][ar] = (double)av1.x;  As[ak + 5][ar] = (double)av1.y;
        As[ak + 6][ar] = (double)av1.z;  As[ak + 7][ar] = (double)av1.w;
        *(double2*)&Ws[wr][col0] = make_double2((double)wv.x, (double)wv.y);
        *(double2*)&Ws[wr][col1] = make_double2((double)wv.z, (double)wv.w);
        __syncthreads();
        if (k0 + 16 < K) {
            av0 = *(const float4*)(apBase + k0 + 16);
            av1 = *(const float4*)(apBase + k0 + 20);
            wv  = *(const float4*)(wpBase + (size_t)(k0 + 16) * ldb);
        }
#pragma unroll
        for (int kk = 0; kk < 16; ++kk) {
            const double* arp = &As[kk][ty * 8];
            double a[8];
#pragma unroll
            for (int t = 0; t < 8; ++t) a[t] = arp[t];
            double2 b01 = *(const double2*)&Ws[kk][col0];
            double2 b23 = *(const double2*)&Ws[kk][col1];
            double b[4] = {b01.x, b01.y, b23.x, b23.y};
#pragma unroll
            for (int i = 0; i < 8; ++i)
#pragma unroll
                for (int j = 0; j < 4; ++j)
                    acc[i][j] = fma(a[i], b[j], acc[i][j]);
        }
    }
#pragma unroll
    for (int i = 0; i < 8; ++i) {
        const size_t row = bm + ty * 8 + i;
        float o[4];
        if (P2 == nullptr) {
#pragma unroll
            for (int j = 0; j < 4; ++j) {
                float mm = (float)acc[i][j];
                float v  = __fadd_rn(mm, P1[bn + tx * 4 + j]);
                o[j] = fmaxf(v, 0.f);
            }
        } else {
            const float z2 = P1[row];
#pragma unroll
            for (int j = 0; j < 4; ++j) {
                float m32  = (float)acc[i][j];
                float twom = __fmul_rn(2.0f, m32);
                float t    = __fsub_rn(z2, twom);
                o[j] = __fadd_rn(t, P2[bn + tx * 4 + j]);
            }
        }
        *(float4*)(C + row * (size_t)ldc + bn + tx * 4) = make_float4(o[0], o[1], o[2], o[3]);
    }
}

// ---------- E transpose ----------
__global__ __launch_bounds__(256)
void transpose_f32(const float* __restrict__ in, float* __restrict__ out)
{
    int i = blockIdx.x * 256 + threadIdx.x;
    int r = i & 255, k = i >> 8;
    out[i] = in[r * 512 + k];
}

// ---------- numpy-pairwise f32 row sum-of-squares (bit-exact) ----------
__device__ __forceinline__ float np_pairwise_sq_512(const float* __restrict__ p)
{
    float b[4];
#pragma unroll
    for (int blk = 0; blk < 4; ++blk) {
        const float* q = p + blk * 128;
        float r[8];
#pragma unroll
        for (int j = 0; j < 8; ++j) { float v = q[j]; r[j] = __fmul_rn(v, v); }
        for (int t = 1; t < 16; ++t)
#pragma unroll
            for (int j = 0; j < 8; ++j) {
                float v = q[8 * t + j];
                r[j] = __fadd_rn(r[j], __fmul_rn(v, v));
            }
        float s01 = __fadd_rn(r[0], r[1]), s23 = __fadd_rn(r[2], r[3]);
        float s45 = __fadd_rn(r[4], r[5]), s67 = __fadd_rn(r[6], r[7]);
        b[blk] = __fadd_rn(__fadd_rn(s01, s23), __fadd_rn(s45, s67));
    }
    return __fadd_rn(__fadd_rn(b[0], b[1]), __fadd_rn(b[2], b[3]));
}

__global__ __launch_bounds__(256)
void rowsq_np(const float* __restrict__ a, float* __restrict__ out, int nrows)
{
    int r = blockIdx.x * 256 + threadIdx.x;
    if (r >= nrows) return;
    out[r] = np_pairwise_sq_512(a + (size_t)r * 512);
}

__global__ __launch_bounds__(256)
void rowsq_c(const float* __restrict__ zc, float* __restrict__ z2c,
             const int* __restrict__ cnt, int base)
{
    int r = blockIdx.x * 256 + threadIdx.x;
    int nn = *cnt - base;
    nn = nn < 0 ? 0 : (nn > CAP ? CAP : nn);
    if (r >= nn) return;
    z2c[r] = np_pairwise_sq_512(zc + (size_t)r * 512);
}

__global__ void zero_counter(int* __restrict__ c) { if (threadIdx.x == 0) *c = 0; }

// ---------- margin-gated argmin -> qb only (r18-proven) ----------
__global__ __launch_bounds__(256)
void argmin_margin(const float* __restrict__ s, const float* __restrict__ E,
                   short* __restrict__ qb, int* __restrict__ slist, int* __restrict__ counter)
{
    const int wave = threadIdx.x >> 6;
    const int lane = threadIdx.x & 63;
    const size_t row = (size_t)blockIdx.x * 4 + wave;
    const float* srow = s + row * 256;
    float m1 = 3.0e38f, m2 = 3.0e38f;
    int i1 = 0;
#pragma unroll
    for (int t = 0; t < 4; ++t) {
        int i = lane + t * 64;
        float v = srow[i];
        if (v < m1 || (v == m1 && i < i1)) { m2 = m1; m1 = v; i1 = i; }
        else m2 = fminf(m2, v);
    }
#pragma unroll
    for (int mm = 32; mm; mm >>= 1) {
        float o1 = __shfl_xor(m1, mm);
        int   oi = __shfl_xor(i1, mm);
        float o2 = __shfl_xor(m2, mm);
        if (o1 < m1 || (o1 == m1 && oi < i1)) { m2 = fminf(m1, o2); m1 = o1; i1 = oi; }
        else m2 = fminf(m2, o1);
    }
    if (m2 - m1 > TAU) {
        const float4* er = (const float4*)(E + (size_t)i1 * 512);
        float4 e0 = er[lane * 2], e1 = er[lane * 2 + 1];
        bf16x8 bv8;
        bv8[0] = f2bf(e0.x); bv8[1] = f2bf(e0.y); bv8[2] = f2bf(e0.z); bv8[3] = f2bf(e0.w);
        bv8[4] = f2bf(e1.x); bv8[5] = f2bf(e1.y); bv8[6] = f2bf(e1.z); bv8[7] = f2bf(e1.w);
        *(bf16x8*)&qb[row * 512 + lane * 8] = bv8;
    } else if (lane == 0) {
        int slot = atomicAdd(counter, 1);
        slist[slot] = (int)row;
    }
}

// ---------- gather suspect x rows -> compact xc ----------
__global__ __launch_bounds__(256)
void gather_xc(const float* __restrict__ x, const int* __restrict__ slist,
               const int* __restrict__ cnt, int base, float* __restrict__ xc)
{
    int b = blockIdx.x;
    if (base + b >= *cnt) return;
    int r = slist[base + b];
    const float4* src = (const float4*)(x + (size_t)(2 * r) * 1024);
    float4* dst = (float4*)(xc + (size_t)(2 * b) * 1024);
    dst[threadIdx.x]       = src[threadIdx.x];
    dst[threadIdx.x + 256] = src[threadIdx.x + 256];
}

// ---------- exact argmin over compacted d2 + scatter qb (r18-proven) ----------
__global__ __launch_bounds__(256)
void argmin_scatter(const float* __restrict__ d2c, const float* __restrict__ E,
                    short* __restrict__ qb, const int* __restrict__ slist,
                    const int* __restrict__ cnt, int base)
{
    const int wave = threadIdx.x >> 6;
    const int lane = threadIdx.x & 63;
    const int b = blockIdx.x * 4 + wave;
    if (base + b >= *cnt) return;
    const int r = slist[base + b];
    const float* srow = d2c + (size_t)b * 256;
    float bv = srow[lane];
    int bi = lane;
#pragma unroll
    for (int t = 1; t < 4; ++t) {
        int i = lane + t * 64;
        float v = srow[i];
        if (v < bv) { bv = v; bi = i; }
    }
#pragma unroll
    for (int m = 32; m; m >>= 1) {
        float ov = __shfl_xor(bv, m);
        int oi = __shfl_xor(bi, m);
        if (ov < bv || (ov == bv && oi < bi)) { bv = ov; bi = oi; }
    }
    const float4* er = (const float4*)(E + (size_t)bi * 512);
    float4 e0 = er[lane * 2], e1 = er[lane * 2 + 1];
    bf16x8 bv8;
    bv8[0] = f2bf(e0.x); bv8[1] = f2bf(e0.y); bv8[2] = f2bf(e0.z); bv8[3] = f2bf(e0.w);
    bv8[4] = f2bf(e1.x); bv8[5] = f2bf(e1.y); bv8[6] = f2bf(e1.z); bv8[7] = f2bf(e1.w);
    *(bf16x8*)&qb[(size_t)r * 512 + lane * 8] = bv8;
}

// ---------- loss: z f32 vs qb bf16 (r18-proven) ----------
__global__ __launch_bounds__(256)
void loss_partial(const float* __restrict__ z, const short* __restrict__ qb,
                  double* __restrict__ partials, long n4)
{
    const float4* z4 = (const float4*)z;
    double s = 0.0;
    for (long i = (long)blockIdx.x * 256 + threadIdx.x; i < n4; i += (long)gridDim.x * 256) {
        float4 a = z4[i];
        const unsigned short* qp = (const unsigned short*)(qb + i * 4);
        double dx = (double)a.x - (double)bf2f(qp[0]);
        double dy = (double)a.y - (double)bf2f(qp[1]);
        double dz = (double)a.z - (double)bf2f(qp[2]);
        double dw = (double)a.w - (double)bf2f(qp[3]);
        s += dx * dx + dy * dy + dz * dz + dw * dw;
    }
    __shared__ double red[256];
    red[threadIdx.x] = s;
    __syncthreads();
    for (int off = 128; off; off >>= 1) {
        if (threadIdx.x < off) red[threadIdx.x] += red[threadIdx.x + off];
        __syncthreads();
    }
    if (threadIdx.x == 0) partials[blockIdx.x] = red[0];
}

__global__ __launch_bounds__(256)
void loss_final(const double* __restrict__ partials, float* __restrict__ out)
{
    __shared__ double red[256];
    double s = 0.0;
    for (int i = threadIdx.x; i < 1024; i += 256) s += partials[i];
    red[threadIdx.x] = s;
    __syncthreads();
    for (int off = 128; off; off >>= 1) {
        if (threadIdx.x < off) red[threadIdx.x] += red[threadIdx.x + off];
        __syncthreads();
    }
    if (threadIdx.x == 0) out[0] = (float)(red[0] * (1.25 / 16777216.0));
}

// ---------- transpose f32 [K][N] -> bf16 [N][K] ----------
__global__ __launch_bounds__(256)
void transpose_bf16(const float* __restrict__ in, short* __restrict__ out,
                    int N, int kshift, long total)
{
    long i = (long)blockIdx.x * 256 + threadIdx.x;
    if (i >= total) return;
    int k = (int)(i & ((1 << kshift) - 1));
    int n = (int)(i >> kshift);
    out[i] = f2bf(in[(size_t)k * N + n]);
}

// ---------- decoder GEMM via bf16 MFMA (round-8 proven) ----------
template<bool RELU, bool OUTBF16>
__global__ __launch_bounds__(256)
void gemm_dec_bf16(const short* __restrict__ A, const short* __restrict__ Bt,
                   const float* __restrict__ bias, void* __restrict__ Cout,
                   int N, int K)
{
    __shared__ short As[128][72];
    __shared__ short Bs[128][72];
    const int tid = threadIdx.x;
    const int lane = tid & 63;
    const int wave = tid >> 6;
    const int wm = (wave >> 1) * 64;
    const int wn = (wave & 1) * 64;
    const size_t bm = (size_t)blockIdx.x * 128;
    const size_t bn = (size_t)blockIdx.y * 128;
    const int fr = lane & 15;
    const int fk8 = (lane >> 4) * 8;

    f32x4 acc[4][4];
#pragma unroll
    for (int m = 0; m < 4; ++m)
#pragma unroll
        for (int n = 0; n < 4; ++n) acc[m][n] = (f32x4)0.f;

    const int sr = tid >> 1;
    const int sk = (tid & 1) * 32;

    for (int k0 = 0; k0 < K; k0 += 64) {
        const uint4* ap4 = (const uint4*)(A + (bm + sr) * (size_t)K + k0 + sk);
        const uint4* bp4 = (const uint4*)(Bt + (bn + sr) * (size_t)K + k0 + sk);
        uint4 av[4], bv[4];
#pragma unroll
        for (int j = 0; j < 4; ++j) { av[j] = ap4[j]; bv[j] = bp4[j]; }
        __syncthreads();
#pragma unroll
        for (int j = 0; j < 4; ++j) {
            *(uint4*)&As[sr][sk + 8 * j] = av[j];
            *(uint4*)&Bs[sr][sk + 8 * j] = bv[j];
        }
        __syncthreads();
#pragma unroll
        for (int kk = 0; kk < 2; ++kk) {
            bf16x8 a[4], b[4];
#pragma unroll
            for (int m = 0; m < 4; ++m)
                a[m] = *(const bf16x8*)&As[wm + m * 16 + fr][kk * 32 + fk8];
#pragma unroll
            for (int n = 0; n < 4; ++n)
                b[n] = *(const bf16x8*)&Bs[wn + n * 16 + fr][kk * 32 + fk8];
#pragma unroll
            for (int m = 0; m < 4; ++m)
#pragma unroll
                for (int n = 0; n < 4; ++n)
                    acc[m][n] = __builtin_amdgcn_mfma_f32_16x16x32_bf16(a[m], b[n], acc[m][n], 0, 0, 0);
        }
    }
#pragma unroll
    for (int m = 0; m < 4; ++m)
#pragma unroll
        for (int n = 0; n < 4; ++n)
#pragma unroll
            for (int i = 0; i < 4; ++i) {
                const size_t row = bm + wm + m * 16 + (lane >> 4) * 4 + i;
                const int col = (int)bn + wn + n * 16 + fr;
                float v = acc[m][n][i] + bias[col];
                if (RELU) v = fmaxf(v, 0.f);
                if (OUTBF16) ((short*)Cout)[row * (size_t)N + col] = f2bf(v);
                else         ((float*)Cout)[row * (size_t)N + col] = v;
            }
}

extern "C" void kernel_launch(void* const* d_in, const int* in_sizes, int n_in,
                              void* d_out, int out_size, void* d_ws, size_t ws_size,
                              hipStream_t stream)
{
    const float* x   = (const float*)d_in[0];
    const float* W1  = (const float*)d_in[1];
    const float* b1  = (const float*)d_in[2];
    const float* W2  = (const float*)d_in[3];
    const float* b2  = (const float*)d_in[4];
    const float* E   = (const float*)d_in[5];
    const float* Wd1 = (const float*)d_in[6];
    const float* bd1 = (const float*)d_in[7];
    const float* Wd2 = (const float*)d_in[8];
    const float* bd2 = (const float*)d_in[9];
    float* out = (float*)d_out;

    float* ws = (float*)d_ws;
    float*  h    = ws;                           // fast h' [0, 33.5M); dead after GEMM2
    float*  xc   = ws;                           // compact x [0, 16.8M) after argmin (h dead)
    float*  zc   = ws;                           // compact z [0, 4.2M) (xc dead per chunk)
    float*  d2c  = ws + 4194304;                 // compact d2
    short*  a1b  = (short*)ws;                   // decoder phase (xc dead)
    short*  qb   = (short*)(ws + 16777216);      // bf16 q [16.8M, 33.5M)
    float*  z    = ws + 33554432;                // fast z' f32 [33.5M, 50.3M)
    float*  sbuf = ws + 67108864;                // s' scores; later hc; later Wd1t/Wd2t
    float*  hc   = ws + 67108864;                // compact h on dead sbuf
    short*  Wd1t = (short*)(ws + 67108864);      // decoder phase (hc dead)
    short*  Wd2t = (short*)(ws + 67108864 + 65536);
    float*  e2v  = ws + 75530240;                // 256
    double* partials = (double*)(ws + 75530496); // 1024 f64
    float*  Et   = ws + 75532544;                // 131,072
    int*    slist   = (int*)(ws + 75663616);     // 32,768
    int*    counter = (int*)(ws + 75696384);     // 1
    float*  z2c  = ws + 75696640;                // 8,192

    dim3 blk(256);
    // fast f32 path (r17-proven)
    gemm_f32t<0><<<dim3(512, 4), blk, 0, stream>>>(x, W1, b1, h, 1024, 512, 512, 1024);
    gemm_f32t<0><<<dim3(512, 2), blk, 0, stream>>>(h, W2, b2, z, 512, 256, 256, 512);
    transpose_f32<<<dim3(512), blk, 0, stream>>>(E, Et);
    rowsq_np<<<dim3(1), blk, 0, stream>>>(E, e2v, 256);
    gemm_f32t<1><<<dim3(256, 2), blk, 0, stream>>>(z, Et, e2v, sbuf, 512, 256, 256, 512);
    // margin-gated argmin (TAU=2e-4: 10x headroom over f32-path noise ~2e-5)
    zero_counter<<<dim3(1), dim3(64), 0, stream>>>(counter);
    argmin_margin<<<dim3(8192), blk, 0, stream>>>(sbuf, E, qb, slist, counter);
    // bit-exact compacted-GEMM recompute, 4 chunks (beyond-n chunks are no-ops)
    for (int c = 0; c < 4; ++c) {
        const int base = c * CAP;
        gather_xc<<<dim3(CAP), blk, 0, stream>>>(x, slist, counter, base, xc);
        gemm_f64<<<dim3(128, 8), blk, 0, stream>>>(xc, W1, b1, nullptr, hc, 1024, 512, 512, 1024, counter, base, 2);
        gemm_f64<<<dim3(128, 4), blk, 0, stream>>>(hc, W2, b2, nullptr, zc, 512, 256, 256, 512, counter, base, 2);
        rowsq_c<<<dim3(32), blk, 0, stream>>>(zc, z2c, counter, base);
        gemm_f64<<<dim3(64, 4), blk, 0, stream>>>(zc, Et, z2c, e2v, d2c, 512, 256, 256, 512, counter, base, 1);
        argmin_scatter<<<dim3(2048), blk, 0, stream>>>(d2c, E, qb, slist, counter, base);
    }
    // vq_loss = 1.25 * mean((qb - z)^2)
    loss_partial<<<dim3(1024), blk, 0, stream>>>(z, qb, partials, 4194304L);
    loss_final<<<dim3(1), blk, 0, stream>>>(partials, out + (size_t)out_size - 1);
    // decoder weights (sbuf/hc dead)
    transpose_bf16<<<dim3(512), blk, 0, stream>>>(Wd1, Wd1t, 512, 8, 131072L);
    transpose_bf16<<<dim3(2048), blk, 0, stream>>>(Wd2, Wd2t, 1024, 9, 524288L);
    // decoder (bf16 MFMA; zq == q in forward)
    gemm_dec_bf16<true,  true ><<<dim3(512, 4), blk, 0, stream>>>(qb,  Wd1t, bd1, a1b, 512, 256);
    gemm_dec_bf16<false, false><<<dim3(512, 8), blk, 0, stream>>>(a1b, Wd2t, bd2, out, 1024, 512);
}

// Round 20
// 2089.031 us; speedup vs baseline: 1.0977x; 1.0376x over previous
//
#include <hip/hip_runtime.h>

typedef __attribute__((ext_vector_type(4))) float  f32x4;
typedef __attribute__((ext_vector_type(8))) short  bf16x8;

#define TAU 2.0e-4f
#define CAP 8192

__device__ __forceinline__ short f2bf(float f) {
    unsigned u = __builtin_bit_cast(unsigned, f);
    unsigned r = (u + 0x7FFFu + ((u >> 16) & 1u)) >> 16;
    return (short)r;
}
__device__ __forceinline__ float bf2f(unsigned short us) {
    return __builtin_bit_cast(float, (unsigned)us << 16);
}

// ---------- fast f32 GEMM, 128x128x16 tile, 8x8 micro, prefetch (r17/r19-proven) ----------
// EPI 0: C = relu(acc + P1[col])   (encoder)
// EPI 1: C = P1[col] - 2*acc       (VQ score s'; P1 = e2v; z2 cancels in argmin)
template<int EPI>
__global__ __launch_bounds__(256)
void gemm_f32t(const float* __restrict__ A, const float* __restrict__ B,
               const float* __restrict__ P1, float* __restrict__ C,
               int lda, int ldb, int ldc, int K)
{
    __shared__ float As[16][128];
    __shared__ float Ws[16][140];
    const int tid = threadIdx.x;
    const size_t bm = (size_t)blockIdx.x * 128;
    const size_t bn = (size_t)blockIdx.y * 128;
    const int ty = tid >> 4, tx = tid & 15;

    float acc[8][8];
#pragma unroll
    for (int i = 0; i < 8; ++i)
#pragma unroll
        for (int j = 0; j < 8; ++j) acc[i][j] = 0.f;

    const int ar = tid >> 1, ak = (tid & 1) * 8;
    const int wr = tid >> 4, wc = (tid & 15) * 8;
    const int wcs = wc + 4 * ((tid & 15) >> 2);
    const int bcs = tx * 8 + 4 * (tx >> 2);

    const float* apB = A + (bm + ar) * (size_t)lda + ak;
    const float* wpB = B + (size_t)wr * ldb + bn + wc;

    float4 av0 = *(const float4*)(apB);
    float4 av1 = *(const float4*)(apB + 4);
    float4 wv0 = *(const float4*)(wpB);
    float4 wv1 = *(const float4*)(wpB + 4);

    for (int k0 = 0; k0 < K; k0 += 16) {
        __syncthreads();
        As[ak + 0][ar] = av0.x;  As[ak + 1][ar] = av0.y;
        As[ak + 2][ar] = av0.z;  As[ak + 3][ar] = av0.w;
        As[ak + 4][ar] = av1.x;  As[ak + 5][ar] = av1.y;
        As[ak + 6][ar] = av1.z;  As[ak + 7][ar] = av1.w;
        *(float4*)&Ws[wr][wcs]     = wv0;
        *(float4*)&Ws[wr][wcs + 4] = wv1;
        __syncthreads();
        if (k0 + 16 < K) {
            av0 = *(const float4*)(apB + k0 + 16);
            av1 = *(const float4*)(apB + k0 + 20);
            wv0 = *(const float4*)(wpB + (size_t)(k0 + 16) * ldb);
            wv1 = *(const float4*)(wpB + (size_t)(k0 + 16) * ldb + 4);
        }
#pragma unroll
        for (int kk = 0; kk < 16; ++kk) {
            float4 a0 = *(const float4*)&As[kk][ty * 8];
            float4 a1 = *(const float4*)&As[kk][ty * 8 + 4];
            float4 w0 = *(const float4*)&Ws[kk][bcs];
            float4 w1 = *(const float4*)&Ws[kk][bcs + 4];
            float a[8] = {a0.x, a0.y, a0.z, a0.w, a1.x, a1.y, a1.z, a1.w};
            float w[8] = {w0.x, w0.y, w0.z, w0.w, w1.x, w1.y, w1.z, w1.w};
#pragma unroll
            for (int i = 0; i < 8; ++i)
#pragma unroll
                for (int j = 0; j < 8; ++j)
                    acc[i][j] = fmaf(a[i], w[j], acc[i][j]);
        }
    }
#pragma unroll
    for (int i = 0; i < 8; ++i) {
        const size_t row = bm + ty * 8 + i;
        float o[8];
#pragma unroll
        for (int j = 0; j < 8; ++j) {
            if (EPI == 0) o[j] = fmaxf(acc[i][j] + P1[bn + tx * 8 + j], 0.f);
            else          o[j] = fmaf(-2.f, acc[i][j], P1[bn + tx * 8 + j]);
        }
        float4* cp = (float4*)(C + row * (size_t)ldc + bn + tx * 8);
        cp[0] = make_float4(o[0], o[1], o[2], o[3]);
        cp[1] = make_float4(o[4], o[5], o[6], o[7]);
    }
}

// ---------- bit-exact f64 GEMM (r13/r15-proven), early-exit; optional indirect A ----------
// If SL != nullptr: A-row index r in [0, 2n) maps to x row 2*SL[r>>1] + (r&1).
// Active rows = clamp(*cnt, 0, CAP) * mult; tiles beyond exit immediately.
template<bool INDIRECT>
__global__ __launch_bounds__(256, 4)
void gemm_f64(const float* __restrict__ A, const float* __restrict__ B,
              const float* __restrict__ P1, const float* __restrict__ P2,
              float* __restrict__ C, int lda, int ldb, int ldc, int K,
              const int* __restrict__ cnt, int mult, const int* __restrict__ SL)
{
    __shared__ double As[16][128];
    __shared__ double Ws[16][68];
    const int tid = threadIdx.x;
    const size_t bm = (size_t)blockIdx.x * 128;
    int nn = *cnt;
    nn = nn < 0 ? 0 : (nn > CAP ? CAP : nn);
    if ((int)bm >= nn * mult) return;
    const size_t bn = (size_t)blockIdx.y * 64;
    const int ty = tid >> 4, tx = tid & 15;

    double acc[8][4];
#pragma unroll
    for (int i = 0; i < 8; ++i)
#pragma unroll
        for (int j = 0; j < 4; ++j) acc[i][j] = 0.0;

    const int ar = tid >> 1, ak = (tid & 1) * 8;
    const int wr = tid >> 4;
    const int wq = tx * 4;
    const int qh = tx >> 3;
    const int col0 = wq + 2 * qh;
    const int col1 = wq + 2 - 2 * qh;

    size_t arow = bm + ar;
    if (INDIRECT) {
        int fr_ = (int)bm + ar;           // flat h-row index (0..2n)
        int li = fr_ >> 1;
        if (li >= nn) li = 0;             // clamp garbage lanes (values unused downstream)
        arow = (size_t)(2 * SL[li] + (fr_ & 1));
    }
    const float* apBase = A + arow * (size_t)lda + ak;
    const float* wpBase = B + (size_t)wr * ldb + bn + wq;

    float4 av0 = *(const float4*)(apBase);
    float4 av1 = *(const float4*)(apBase + 4);
    float4 wv  = *(const float4*)(wpBase);

    for (int k0 = 0; k0 < K; k0 += 16) {
        __syncthreads();
        As[ak + 0][ar] = (double)av0.x;  As[ak + 1][ar] = (double)av0.y;
        As[ak + 2][ar] = (double)av0.z;  As[ak + 3][ar] = (double)av0.w;
        As[ak + 4][ar] = (double)av1.x;  As[ak + 5][ar] = (double)av1.y;
        As[ak + 6][ar] = (double)av1.z;  As[ak + 7][ar] = (double)av1.w;
        *(double2*)&Ws[wr][col0] = make_double2((double)wv.x, (double)wv.y);
        *(double2*)&Ws[wr][col1] = make_double2((double)wv.z, (double)wv.w);
        __syncthreads();
        if (k0 + 16 < K) {
            av0 = *(const float4*)(apBase + k0 + 16);
            av1 = *(const float4*)(apBase + k0 + 20);
            wv  = *(const float4*)(wpBase + (size_t)(k0 + 16) * ldb);
        }
#pragma unroll
        for (int kk = 0; kk < 16; ++kk) {
            const double* arp = &As[kk][ty * 8];
            double a[8];
#pragma unroll
            for (int t = 0; t < 8; ++t) a[t] = arp[t];
            double2 b01 = *(const double2*)&Ws[kk][col0];
            double2 b23 = *(const double2*)&Ws[kk][col1];
            double b[4] = {b01.x, b01.y, b23.x, b23.y};
#pragma unroll
            for (int i = 0; i < 8; ++i)
#pragma unroll
                for (int j = 0; j < 4; ++j)
                    acc[i][j] = fma(a[i], b[j], acc[i][j]);
        }
    }
#pragma unroll
    for (int i = 0; i < 8; ++i) {
        const size_t row = bm + ty * 8 + i;
        float o[4];
        if (P2 == nullptr) {   // encoder epilogue (bit-exact round-5 rounding points)
#pragma unroll
            for (int j = 0; j < 4; ++j) {
                float mm = (float)acc[i][j];
                float v  = __fadd_rn(mm, P1[bn + tx * 4 + j]);
                o[j] = fmaxf(v, 0.f);
            }
        } else {               // d2 epilogue
            const float z2 = P1[row];
#pragma unroll
            for (int j = 0; j < 4; ++j) {
                float m32  = (float)acc[i][j];
                float twom = __fmul_rn(2.0f, m32);
                float t    = __fsub_rn(z2, twom);
                o[j] = __fadd_rn(t, P2[bn + tx * 4 + j]);
            }
        }
        *(float4*)(C + row * (size_t)ldc + bn + tx * 4) = make_float4(o[0], o[1], o[2], o[3]);
    }
}

// ---------- E transpose + counter zero ----------
__global__ __launch_bounds__(256)
void transpose_f32(const float* __restrict__ in, float* __restrict__ out,
                   int* __restrict__ counter)
{
    int i = blockIdx.x * 256 + threadIdx.x;
    if (i == 0) *counter = 0;
    int r = i & 255, k = i >> 8;
    out[i] = in[r * 512 + k];
}

// ---------- numpy-pairwise f32 row sum-of-squares (bit-exact) ----------
__device__ __forceinline__ float np_pairwise_sq_512(const float* __restrict__ p)
{
    float b[4];
#pragma unroll
    for (int blk = 0; blk < 4; ++blk) {
        const float* q = p + blk * 128;
        float r[8];
#pragma unroll
        for (int j = 0; j < 8; ++j) { float v = q[j]; r[j] = __fmul_rn(v, v); }
        for (int t = 1; t < 16; ++t)
#pragma unroll
            for (int j = 0; j < 8; ++j) {
                float v = q[8 * t + j];
                r[j] = __fadd_rn(r[j], __fmul_rn(v, v));
            }
        float s01 = __fadd_rn(r[0], r[1]), s23 = __fadd_rn(r[2], r[3]);
        float s45 = __fadd_rn(r[4], r[5]), s67 = __fadd_rn(r[6], r[7]);
        b[blk] = __fadd_rn(__fadd_rn(s01, s23), __fadd_rn(s45, s67));
    }
    return __fadd_rn(__fadd_rn(b[0], b[1]), __fadd_rn(b[2], b[3]));
}

__global__ __launch_bounds__(256)
void rowsq_np(const float* __restrict__ a, float* __restrict__ out, int nrows)
{
    int r = blockIdx.x * 256 + threadIdx.x;
    if (r >= nrows) return;
    out[r] = np_pairwise_sq_512(a + (size_t)r * 512);
}

__global__ __launch_bounds__(256)
void rowsq_c(const float* __restrict__ zc, float* __restrict__ z2c,
             const int* __restrict__ cnt)
{
    int r = blockIdx.x * 256 + threadIdx.x;
    int nn = *cnt;
    nn = nn < 0 ? 0 : (nn > CAP ? CAP : nn);
    if (r >= nn) return;
    z2c[r] = np_pairwise_sq_512(zc + (size_t)r * 512);
}

// ---------- margin-gated argmin -> qb only (r18/r19-proven) ----------
__global__ __launch_bounds__(256)
void argmin_margin(const float* __restrict__ s, const float* __restrict__ E,
                   short* __restrict__ qb, int* __restrict__ slist, int* __restrict__ counter)
{
    const int wave = threadIdx.x >> 6;
    const int lane = threadIdx.x & 63;
    const size_t row = (size_t)blockIdx.x * 4 + wave;
    const float* srow = s + row * 256;
    float m1 = 3.0e38f, m2 = 3.0e38f;
    int i1 = 0;
#pragma unroll
    for (int t = 0; t < 4; ++t) {
        int i = lane + t * 64;
        float v = srow[i];
        if (v < m1 || (v == m1 && i < i1)) { m2 = m1; m1 = v; i1 = i; }
        else m2 = fminf(m2, v);
    }
#pragma unroll
    for (int mm = 32; mm; mm >>= 1) {
        float o1 = __shfl_xor(m1, mm);
        int   oi = __shfl_xor(i1, mm);
        float o2 = __shfl_xor(m2, mm);
        if (o1 < m1 || (o1 == m1 && oi < i1)) { m2 = fminf(m1, o2); m1 = o1; i1 = oi; }
        else m2 = fminf(m2, o1);
    }
    if (m2 - m1 > TAU) {
        const float4* er = (const float4*)(E + (size_t)i1 * 512);
        float4 e0 = er[lane * 2], e1 = er[lane * 2 + 1];
        bf16x8 bv8;
        bv8[0] = f2bf(e0.x); bv8[1] = f2bf(e0.y); bv8[2] = f2bf(e0.z); bv8[3] = f2bf(e0.w);
        bv8[4] = f2bf(e1.x); bv8[5] = f2bf(e1.y); bv8[6] = f2bf(e1.z); bv8[7] = f2bf(e1.w);
        *(bf16x8*)&qb[row * 512 + lane * 8] = bv8;
    } else if (lane == 0) {
        int slot = atomicAdd(counter, 1);
        slist[slot] = (int)row;
    }
}

// ---------- exact argmin over compacted d2 + scatter qb (r18/r19-proven) ----------
__global__ __launch_bounds__(256)
void argmin_scatter(const float* __restrict__ d2c, const float* __restrict__ E,
                    short* __restrict__ qb, const int* __restrict__ slist,
                    const int* __restrict__ cnt)
{
    const int wave = threadIdx.x >> 6;
    const int lane = threadIdx.x & 63;
    const int b = blockIdx.x * 4 + wave;
    if (b >= *cnt) return;
    const int r = slist[b];
    const float* srow = d2c + (size_t)b * 256;
    float bv = srow[lane];
    int bi = lane;
#pragma unroll
    for (int t = 1; t < 4; ++t) {
        int i = lane + t * 64;
        float v = srow[i];
        if (v < bv) { bv = v; bi = i; }
    }
#pragma unroll
    for (int m = 32; m; m >>= 1) {
        float ov = __shfl_xor(bv, m);
        int oi = __shfl_xor(bi, m);
        if (ov < bv || (ov == bv && oi < bi)) { bv = ov; bi = oi; }
    }
    const float4* er = (const float4*)(E + (size_t)bi * 512);
    float4 e0 = er[lane * 2], e1 = er[lane * 2 + 1];
    bf16x8 bv8;
    bv8[0] = f2bf(e0.x); bv8[1] = f2bf(e0.y); bv8[2] = f2bf(e0.z); bv8[3] = f2bf(e0.w);
    bv8[4] = f2bf(e1.x); bv8[5] = f2bf(e1.y); bv8[6] = f2bf(e1.z); bv8[7] = f2bf(e1.w);
    *(bf16x8*)&qb[(size_t)r * 512 + lane * 8] = bv8;
}

// ---------- loss: z f32 vs qb bf16 (r18/r19-proven) ----------
__global__ __launch_bounds__(256)
void loss_partial(const float* __restrict__ z, const short* __restrict__ qb,
                  double* __restrict__ partials, long n4)
{
    const float4* z4 = (const float4*)z;
    double s = 0.0;
    for (long i = (long)blockIdx.x * 256 + threadIdx.x; i < n4; i += (long)gridDim.x * 256) {
        float4 a = z4[i];
        const unsigned short* qp = (const unsigned short*)(qb + i * 4);
        double dx = (double)a.x - (double)bf2f(qp[0]);
        double dy = (double)a.y - (double)bf2f(qp[1]);
        double dz = (double)a.z - (double)bf2f(qp[2]);
        double dw = (double)a.w - (double)bf2f(qp[3]);
        s += dx * dx + dy * dy + dz * dz + dw * dw;
    }
    __shared__ double red[256];
    red[threadIdx.x] = s;
    __syncthreads();
    for (int off = 128; off; off >>= 1) {
        if (threadIdx.x < off) red[threadIdx.x] += red[threadIdx.x + off];
        __syncthreads();
    }
    if (threadIdx.x == 0) partials[blockIdx.x] = red[0];
}

__global__ __launch_bounds__(256)
void loss_final(const double* __restrict__ partials, float* __restrict__ out)
{
    __shared__ double red[256];
    double s = 0.0;
    for (int i = threadIdx.x; i < 1024; i += 256) s += partials[i];
    red[threadIdx.x] = s;
    __syncthreads();
    for (int off = 128; off; off >>= 1) {
        if (threadIdx.x < off) red[threadIdx.x] += red[threadIdx.x + off];
        __syncthreads();
    }
    if (threadIdx.x == 0) out[0] = (float)(red[0] * (1.25 / 16777216.0));
}

// ---------- transpose f32 [K][N] -> bf16 [N][K] ----------
__global__ __launch_bounds__(256)
void transpose_bf16(const float* __restrict__ in, short* __restrict__ out,
                    int N, int kshift, long total)
{
    long i = (long)blockIdx.x * 256 + threadIdx.x;
    if (i >= total) return;
    int k = (int)(i & ((1 << kshift) - 1));
    int n = (int)(i >> kshift);
    out[i] = f2bf(in[(size_t)k * N + n]);
}

// ---------- decoder GEMM via bf16 MFMA (round-8 proven) ----------
template<bool RELU, bool OUTBF16>
__global__ __launch_bounds__(256)
void gemm_dec_bf16(const short* __restrict__ A, const short* __restrict__ Bt,
                   const float* __restrict__ bias, void* __restrict__ Cout,
                   int N, int K)
{
    __shared__ short As[128][72];
    __shared__ short Bs[128][72];
    const int tid = threadIdx.x;
    const int lane = tid & 63;
    const int wave = tid >> 6;
    const int wm = (wave >> 1) * 64;
    const int wn = (wave & 1) * 64;
    const size_t bm = (size_t)blockIdx.x * 128;
    const size_t bn = (size_t)blockIdx.y * 128;
    const int fr = lane & 15;
    const int fk8 = (lane >> 4) * 8;

    f32x4 acc[4][4];
#pragma unroll
    for (int m = 0; m < 4; ++m)
#pragma unroll
        for (int n = 0; n < 4; ++n) acc[m][n] = (f32x4)0.f;

    const int sr = tid >> 1;
    const int sk = (tid & 1) * 32;

    for (int k0 = 0; k0 < K; k0 += 64) {
        const uint4* ap4 = (const uint4*)(A + (bm + sr) * (size_t)K + k0 + sk);
        const uint4* bp4 = (const uint4*)(Bt + (bn + sr) * (size_t)K + k0 + sk);
        uint4 av[4], bv[4];
#pragma unroll
        for (int j = 0; j < 4; ++j) { av[j] = ap4[j]; bv[j] = bp4[j]; }
        __syncthreads();
#pragma unroll
        for (int j = 0; j < 4; ++j) {
            *(uint4*)&As[sr][sk + 8 * j] = av[j];
            *(uint4*)&Bs[sr][sk + 8 * j] = bv[j];
        }
        __syncthreads();
#pragma unroll
        for (int kk = 0; kk < 2; ++kk) {
            bf16x8 a[4], b[4];
#pragma unroll
            for (int m = 0; m < 4; ++m)
                a[m] = *(const bf16x8*)&As[wm + m * 16 + fr][kk * 32 + fk8];
#pragma unroll
            for (int n = 0; n < 4; ++n)
                b[n] = *(const bf16x8*)&Bs[wn + n * 16 + fr][kk * 32 + fk8];
#pragma unroll
            for (int m = 0; m < 4; ++m)
#pragma unroll
                for (int n = 0; n < 4; ++n)
                    acc[m][n] = __builtin_amdgcn_mfma_f32_16x16x32_bf16(a[m], b[n], acc[m][n], 0, 0, 0);
        }
    }
#pragma unroll
    for (int m = 0; m < 4; ++m)
#pragma unroll
        for (int n = 0; n < 4; ++n)
#pragma unroll
            for (int i = 0; i < 4; ++i) {
                const size_t row = bm + wm + m * 16 + (lane >> 4) * 4 + i;
                const int col = (int)bn + wn + n * 16 + fr;
                float v = acc[m][n][i] + bias[col];
                if (RELU) v = fmaxf(v, 0.f);
                if (OUTBF16) ((short*)Cout)[row * (size_t)N + col] = f2bf(v);
                else         ((float*)Cout)[row * (size_t)N + col] = v;
            }
}

extern "C" void kernel_launch(void* const* d_in, const int* in_sizes, int n_in,
                              void* d_out, int out_size, void* d_ws, size_t ws_size,
                              hipStream_t stream)
{
    const float* x   = (const float*)d_in[0];
    const float* W1  = (const float*)d_in[1];
    const float* b1  = (const float*)d_in[2];
    const float* W2  = (const float*)d_in[3];
    const float* b2  = (const float*)d_in[4];
    const float* E   = (const float*)d_in[5];
    const float* Wd1 = (const float*)d_in[6];
    const float* bd1 = (const float*)d_in[7];
    const float* Wd2 = (const float*)d_in[8];
    const float* bd2 = (const float*)d_in[9];
    float* out = (float*)d_out;

    float* ws = (float*)d_ws;
    float*  h    = ws;                           // fast h' [0, 33.5M); dead after GEMM2
    // recompute overlays on dead h (post-argmin):
    float*  hc   = ws;                           // [0, 8,388,608)  compact h (2*CAP x 512)
    float*  zc   = ws + 8388608;                 // [8.4M, 12.6M)   compact z (CAP x 512)
    float*  d2c  = ws + 12582912;                // [12.6M, 14.7M)  compact d2 (CAP x 256)
    float*  z2c  = ws + 14680064;                // [14.7M, +8192)
    short*  a1b  = (short*)ws;                   // decoder phase (all above dead)
    short*  qb   = (short*)(ws + 16777216);      // bf16 q [16.8M, 33.5M)
    float*  z    = ws + 33554432;                // fast z' f32 [33.5M, 50.3M)
    float*  sbuf = ws + 67108864;                // s' scores [67.1M, 75.5M); dead after argmin
    short*  Wd1t = (short*)(ws + 67108864);      // decoder phase (sbuf dead)
    short*  Wd2t = (short*)(ws + 67108864 + 65536);
    float*  e2v  = ws + 75530240;                // 256
    double* partials = (double*)(ws + 75530496); // 1024 f64
    float*  Et   = ws + 75532544;                // 131,072
    int*    slist   = (int*)(ws + 75663616);     // 32,768
    int*    counter = (int*)(ws + 75696384);     // 1

    dim3 blk(256);
    // fast f32 path (r17/r19-proven)
    gemm_f32t<0><<<dim3(512, 4), blk, 0, stream>>>(x, W1, b1, h, 1024, 512, 512, 1024);
    gemm_f32t<0><<<dim3(512, 2), blk, 0, stream>>>(h, W2, b2, z, 512, 256, 256, 512);
    transpose_f32<<<dim3(512), blk, 0, stream>>>(E, Et, counter);   // also zeroes counter
    rowsq_np<<<dim3(1), blk, 0, stream>>>(E, e2v, 256);
    gemm_f32t<1><<<dim3(256, 2), blk, 0, stream>>>(z, Et, e2v, sbuf, 512, 256, 256, 512);
    // margin-gated argmin (TAU=2e-4, r19-proven)
    argmin_margin<<<dim3(8192), blk, 0, stream>>>(sbuf, E, qb, slist, counter);
    // bit-exact recompute, single-shot via indirect-A (n <= CAP; n measured ~1k scale)
    gemm_f64<true ><<<dim3(128, 8), blk, 0, stream>>>(x,  W1, b1, nullptr, hc, 1024, 512, 512, 1024, counter, 2, slist);
    gemm_f64<false><<<dim3(128, 4), blk, 0, stream>>>(hc, W2, b2, nullptr, zc,  512, 256, 256,  512, counter, 2, nullptr);
    rowsq_c<<<dim3(32), blk, 0, stream>>>(zc, z2c, counter);
    gemm_f64<false><<<dim3(64, 4), blk, 0, stream>>>(zc, Et, z2c, e2v, d2c, 512, 256, 256, 512, counter, 1, nullptr);
    argmin_scatter<<<dim3(2048), blk, 0, stream>>>(d2c, E, qb, slist, counter);
    // vq_loss = 1.25 * mean((qb - z)^2)
    loss_partial<<<dim3(1024), blk, 0, stream>>>(z, qb, partials, 4194304L);
    loss_final<<<dim3(1), blk, 0, stream>>>(partials, out + (size_t)out_size - 1);
    // decoder weights (sbuf dead)
    transpose_bf16<<<dim3(512), blk, 0, stream>>>(Wd1, Wd1t, 512, 8, 131072L);
    transpose_bf16<<<dim3(2048), blk, 0, stream>>>(Wd2, Wd2t, 1024, 9, 524288L);
    // decoder (bf16 MFMA; zq == q in forward)
    gemm_dec_bf16<true,  true ><<<dim3(512, 4), blk, 0, stream>>>(qb,  Wd1t, bd1, a1b, 512, 256);
    gemm_dec_bf16<false, false><<<dim3(512, 8), blk, 0, stream>>>(a1b, Wd2t, bd2, out, 1024, 512);
}

// Round 23
// 1605.574 us; speedup vs baseline: 1.4282x; 1.3011x over previous
//
#include <hip/hip_runtime.h>

typedef __attribute__((ext_vector_type(4))) float  f32x4;
typedef __attribute__((ext_vector_type(8))) short  bf16x8;

#define TAU 2.0e-4f
#define CAP 8192

__device__ __forceinline__ short f2bf(float f) {
    unsigned u = __builtin_bit_cast(unsigned, f);
    unsigned r = (u + 0x7FFFu + ((u >> 16) & 1u)) >> 16;
    return (short)r;
}
__device__ __forceinline__ float bf2f(unsigned short us) {
    return __builtin_bit_cast(float, (unsigned)us << 16);
}

// ---------- weight split: f32 [K][N] -> bf16 hi/lo [N][K] ----------
__global__ __launch_bounds__(256)
void split_w(const float* __restrict__ in, short* __restrict__ outh,
             short* __restrict__ outl, int N, int kshift, long total)
{
    long i = (long)blockIdx.x * 256 + threadIdx.x;
    if (i >= total) return;
    int k = (int)(i & ((1 << kshift) - 1));
    int n = (int)(i >> kshift);
    float v = in[(size_t)k * N + n];
    short hi = f2bf(v);
    outh[i] = hi;
    outl[i] = f2bf(v - bf2f((unsigned short)hi));
}

// ---------- bf16x3 split-MFMA GEMM1 only: C = relu(acc + bias) f32 ----------
// acc += Al*Bh + Ah*Bl + Ah*Bh (lo*lo dropped, ~2^-16 relative).
// LDS rows 40 shorts = 80 B: all 16B accesses aligned; 2-way banks (free).
__global__ __launch_bounds__(256)
void gemm_bf3g1(const float* __restrict__ A, const short* __restrict__ Bh,
                const short* __restrict__ Bl, const float* __restrict__ bias,
                float* __restrict__ C, int lda, int ldc, int K)
{
    __shared__ short Ash[128][40];
    __shared__ short Asl[128][40];
    __shared__ short Bsh[128][40];
    __shared__ short Bsl[128][40];
    const int tid = threadIdx.x;
    const int lane = tid & 63;
    const int wave = tid >> 6;
    const int wm = (wave >> 1) * 64;
    const int wn = (wave & 1) * 64;
    const size_t bm = (size_t)blockIdx.x * 128;
    const size_t bn = (size_t)blockIdx.y * 128;
    const int fr = lane & 15;
    const int fk8 = (lane >> 4) * 8;

    f32x4 acc[4][4];
#pragma unroll
    for (int m = 0; m < 4; ++m)
#pragma unroll
        for (int n = 0; n < 4; ++n) acc[m][n] = (f32x4)0.f;

    const int sr = tid >> 1;          // staging row 0..127
    const int sk = (tid & 1) * 16;    // k-chunk 0/16

    const float* apB = A + (bm + sr) * (size_t)lda + sk;
    const short* bhB = Bh + (bn + sr) * (size_t)K + sk;
    const short* blB = Bl + (bn + sr) * (size_t)K + sk;

    float4 av0 = *(const float4*)(apB);
    float4 av1 = *(const float4*)(apB + 4);
    float4 av2 = *(const float4*)(apB + 8);
    float4 av3 = *(const float4*)(apB + 12);
    bf16x8 pbh0 = *(const bf16x8*)(bhB);
    bf16x8 pbh1 = *(const bf16x8*)(bhB + 8);
    bf16x8 pbl0 = *(const bf16x8*)(blB);
    bf16x8 pbl1 = *(const bf16x8*)(blB + 8);

    for (int k0 = 0; k0 < K; k0 += 32) {
        __syncthreads();
        {
            float va[16] = {av0.x, av0.y, av0.z, av0.w, av1.x, av1.y, av1.z, av1.w,
                            av2.x, av2.y, av2.z, av2.w, av3.x, av3.y, av3.z, av3.w};
            bf16x8 h0, h1, l0, l1;
#pragma unroll
            for (int e = 0; e < 8; ++e) {
                float v = va[e];
                short hi = f2bf(v);
                h0[e] = hi;
                l0[e] = f2bf(v - bf2f((unsigned short)hi));
            }
#pragma unroll
            for (int e = 0; e < 8; ++e) {
                float v = va[8 + e];
                short hi = f2bf(v);
                h1[e] = hi;
                l1[e] = f2bf(v - bf2f((unsigned short)hi));
            }
            *(bf16x8*)&Ash[sr][sk]     = h0;
            *(bf16x8*)&Ash[sr][sk + 8] = h1;
            *(bf16x8*)&Asl[sr][sk]     = l0;
            *(bf16x8*)&Asl[sr][sk + 8] = l1;
            *(bf16x8*)&Bsh[sr][sk]     = pbh0;
            *(bf16x8*)&Bsh[sr][sk + 8] = pbh1;
            *(bf16x8*)&Bsl[sr][sk]     = pbl0;
            *(bf16x8*)&Bsl[sr][sk + 8] = pbl1;
        }
        __syncthreads();
        if (k0 + 32 < K) {
            av0 = *(const float4*)(apB + k0 + 32);
            av1 = *(const float4*)(apB + k0 + 36);
            av2 = *(const float4*)(apB + k0 + 40);
            av3 = *(const float4*)(apB + k0 + 44);
            pbh0 = *(const bf16x8*)(bhB + k0 + 32);
            pbh1 = *(const bf16x8*)(bhB + k0 + 40);
            pbl0 = *(const bf16x8*)(blB + k0 + 32);
            pbl1 = *(const bf16x8*)(blB + k0 + 40);
        }
        bf16x8 ah[4], al[4], bhf[4], blf[4];
#pragma unroll
        for (int m = 0; m < 4; ++m) {
            ah[m] = *(const bf16x8*)&Ash[wm + m * 16 + fr][fk8];
            al[m] = *(const bf16x8*)&Asl[wm + m * 16 + fr][fk8];
        }
#pragma unroll
        for (int n = 0; n < 4; ++n) {
            bhf[n] = *(const bf16x8*)&Bsh[wn + n * 16 + fr][fk8];
            blf[n] = *(const bf16x8*)&Bsl[wn + n * 16 + fr][fk8];
        }
#pragma unroll
        for (int m = 0; m < 4; ++m)
#pragma unroll
            for (int n = 0; n < 4; ++n) {
                acc[m][n] = __builtin_amdgcn_mfma_f32_16x16x32_bf16(al[m], bhf[n], acc[m][n], 0, 0, 0);
                acc[m][n] = __builtin_amdgcn_mfma_f32_16x16x32_bf16(ah[m], blf[n], acc[m][n], 0, 0, 0);
                acc[m][n] = __builtin_amdgcn_mfma_f32_16x16x32_bf16(ah[m], bhf[n], acc[m][n], 0, 0, 0);
            }
    }
#pragma unroll
    for (int m = 0; m < 4; ++m)
#pragma unroll
        for (int n = 0; n < 4; ++n)
#pragma unroll
            for (int i = 0; i < 4; ++i) {
                const size_t row = bm + wm + m * 16 + (lane >> 4) * 4 + i;
                const int col = (int)bn + wn + n * 16 + fr;
                C[row * (size_t)ldc + col] = fmaxf(acc[m][n][i] + bias[col], 0.f);
            }
}

// ---------- fast f32 GEMM (r17/r19/r20-proven) ----------
template<int EPI>
__global__ __launch_bounds__(256)
void gemm_f32t(const float* __restrict__ A, const float* __restrict__ B,
               const float* __restrict__ P1, float* __restrict__ C,
               int lda, int ldb, int ldc, int K)
{
    __shared__ float As[16][128];
    __shared__ float Ws[16][140];
    const int tid = threadIdx.x;
    const size_t bm = (size_t)blockIdx.x * 128;
    const size_t bn = (size_t)blockIdx.y * 128;
    const int ty = tid >> 4, tx = tid & 15;

    float acc[8][8];
#pragma unroll
    for (int i = 0; i < 8; ++i)
#pragma unroll
        for (int j = 0; j < 8; ++j) acc[i][j] = 0.f;

    const int ar = tid >> 1, ak = (tid & 1) * 8;
    const int wr = tid >> 4, wc = (tid & 15) * 8;
    const int wcs = wc + 4 * ((tid & 15) >> 2);
    const int bcs = tx * 8 + 4 * (tx >> 2);

    const float* apB = A + (bm + ar) * (size_t)lda + ak;
    const float* wpB = B + (size_t)wr * ldb + bn + wc;

    float4 av0 = *(const float4*)(apB);
    float4 av1 = *(const float4*)(apB + 4);
    float4 wv0 = *(const float4*)(wpB);
    float4 wv1 = *(const float4*)(wpB + 4);

    for (int k0 = 0; k0 < K; k0 += 16) {
        __syncthreads();
        As[ak + 0][ar] = av0.x;  As[ak + 1][ar] = av0.y;
        As[ak + 2][ar] = av0.z;  As[ak + 3][ar] = av0.w;
        As[ak + 4][ar] = av1.x;  As[ak + 5][ar] = av1.y;
        As[ak + 6][ar] = av1.z;  As[ak + 7][ar] = av1.w;
        *(float4*)&Ws[wr][wcs]     = wv0;
        *(float4*)&Ws[wr][wcs + 4] = wv1;
        __syncthreads();
        if (k0 + 16 < K) {
            av0 = *(const float4*)(apB + k0 + 16);
            av1 = *(const float4*)(apB + k0 + 20);
            wv0 = *(const float4*)(wpB + (size_t)(k0 + 16) * ldb);
            wv1 = *(const float4*)(wpB + (size_t)(k0 + 16) * ldb + 4);
        }
#pragma unroll
        for (int kk = 0; kk < 16; ++kk) {
            float4 a0 = *(const float4*)&As[kk][ty * 8];
            float4 a1 = *(const float4*)&As[kk][ty * 8 + 4];
            float4 w0 = *(const float4*)&Ws[kk][bcs];
            float4 w1 = *(const float4*)&Ws[kk][bcs + 4];
            float a[8] = {a0.x, a0.y, a0.z, a0.w, a1.x, a1.y, a1.z, a1.w};
            float w[8] = {w0.x, w0.y, w0.z, w0.w, w1.x, w1.y, w1.z, w1.w};
#pragma unroll
            for (int i = 0; i < 8; ++i)
#pragma unroll
                for (int j = 0; j < 8; ++j)
                    acc[i][j] = fmaf(a[i], w[j], acc[i][j]);
        }
    }
#pragma unroll
    for (int i = 0; i < 8; ++i) {
        const size_t row = bm + ty * 8 + i;
        float o[8];
#pragma unroll
        for (int j = 0; j < 8; ++j) {
            if (EPI == 0) o[j] = fmaxf(acc[i][j] + P1[bn + tx * 8 + j], 0.f);
            else          o[j] = fmaf(-2.f, acc[i][j], P1[bn + tx * 8 + j]);
        }
        float4* cp = (float4*)(C + row * (size_t)ldc + bn + tx * 8);
        cp[0] = make_float4(o[0], o[1], o[2], o[3]);
        cp[1] = make_float4(o[4], o[5], o[6], o[7]);
    }
}

// ---------- bit-exact f64 GEMM (r13/r15-proven), early-exit; optional indirect A ----------
template<bool INDIRECT>
__global__ __launch_bounds__(256, 4)
void gemm_f64(const float* __restrict__ A, const float* __restrict__ B,
              const float* __restrict__ P1, const float* __restrict__ P2,
              float* __restrict__ C, int lda, int ldb, int ldc, int K,
              const int* __restrict__ cnt, int mult, const int* __restrict__ SL)
{
    __shared__ double As[16][128];
    __shared__ double Ws[16][68];
    const int tid = threadIdx.x;
    const size_t bm = (size_t)blockIdx.x * 128;
    int nn = *cnt;
    nn = nn < 0 ? 0 : (nn > CAP ? CAP : nn);
    if ((int)bm >= nn * mult) return;
    const size_t bn = (size_t)blockIdx.y * 64;
    const int ty = tid >> 4, tx = tid & 15;

    double acc[8][4];
#pragma unroll
    for (int i = 0; i < 8; ++i)
#pragma unroll
        for (int j = 0; j < 4; ++j) acc[i][j] = 0.0;

    const int ar = tid >> 1, ak = (tid & 1) * 8;
    const int wr = tid >> 4;
    const int wq = tx * 4;
    const int qh = tx >> 3;
    const int col0 = wq + 2 * qh;
    const int col1 = wq + 2 - 2 * qh;

    size_t arow = bm + ar;
    if (INDIRECT) {
        int fr_ = (int)bm + ar;
        int li = fr_ >> 1;
        if (li >= nn) li = 0;
        arow = (size_t)(2 * SL[li] + (fr_ & 1));
    }
    const float* apBase = A + arow * (size_t)lda + ak;
    const float* wpBase = B + (size_t)wr * ldb + bn + wq;

    float4 av0 = *(const float4*)(apBase);
    float4 av1 = *(const float4*)(apBase + 4);
    float4 wv  = *(const float4*)(wpBase);

    for (int k0 = 0; k0 < K; k0 += 16) {
        __syncthreads();
        As[ak + 0][ar] = (double)av0.x;  As[ak + 1][ar] = (double)av0.y;
        As[ak + 2][ar] = (double)av0.z;  As[ak + 3][ar] = (double)av0.w;
        As[ak + 4][ar] = (double)av1.x;  As[ak + 5][ar] = (double)av1.y;
        As[ak + 6][ar] = (double)av1.z;  As[ak + 7][ar] = (double)av1.w;
        *(double2*)&Ws[wr][col0] = make_double2((double)wv.x, (double)wv.y);
        *(double2*)&Ws[wr][col1] = make_double2((double)wv.z, (double)wv.w);
        __syncthreads();
        if (k0 + 16 < K) {
            av0 = *(const float4*)(apBase + k0 + 16);
            av1 = *(const float4*)(apBase + k0 + 20);
            wv  = *(const float4*)(wpBase + (size_t)(k0 + 16) * ldb);
        }
#pragma unroll
        for (int kk = 0; kk < 16; ++kk) {
            const double* arp = &As[kk][ty * 8];
            double a[8];
#pragma unroll
            for (int t = 0; t < 8; ++t) a[t] = arp[t];
            double2 b01 = *(const double2*)&Ws[kk][col0];
            double2 b23 = *(const double2*)&Ws[kk][col1];
            double b[4] = {b01.x, b01.y, b23.x, b23.y};
#pragma unroll
            for (int i = 0; i < 8; ++i)
#pragma unroll
                for (int j = 0; j < 4; ++j)
                    acc[i][j] = fma(a[i], b[j], acc[i][j]);
        }
    }
#pragma unroll
    for (int i = 0; i < 8; ++i) {
        const size_t row = bm + ty * 8 + i;
        float o[4];
        if (P2 == nullptr) {
#pragma unroll
            for (int j = 0; j < 4; ++j) {
                float mm = (float)acc[i][j];
                float v  = __fadd_rn(mm, P1[bn + tx * 4 + j]);
                o[j] = fmaxf(v, 0.f);
            }
        } else {
            const float z2 = P1[row];
#pragma unroll
            for (int j = 0; j < 4; ++j) {
                float m32  = (float)acc[i][j];
                float twom = __fmul_rn(2.0f, m32);
                float t    = __fsub_rn(z2, twom);
                o[j] = __fadd_rn(t, P2[bn + tx * 4 + j]);
            }
        }
        *(float4*)(C + row * (size_t)ldc + bn + tx * 4) = make_float4(o[0], o[1], o[2], o[3]);
    }
}

// ---------- E transpose + counter zero ----------
__global__ __launch_bounds__(256)
void transpose_f32(const float* __restrict__ in, float* __restrict__ out,
                   int* __restrict__ counter)
{
    int i = blockIdx.x * 256 + threadIdx.x;
    if (i == 0) *counter = 0;
    int r = i & 255, k = i >> 8;
    out[i] = in[r * 512 + k];
}

// ---------- numpy-pairwise f32 row sum-of-squares (bit-exact) ----------
__device__ __forceinline__ float np_pairwise_sq_512(const float* __restrict__ p)
{
    float b[4];
#pragma unroll
    for (int blk = 0; blk < 4; ++blk) {
        const float* q = p + blk * 128;
        float r[8];
#pragma unroll
        for (int j = 0; j < 8; ++j) { float v = q[j]; r[j] = __fmul_rn(v, v); }
        for (int t = 1; t < 16; ++t)
#pragma unroll
            for (int j = 0; j < 8; ++j) {
                float v = q[8 * t + j];
                r[j] = __fadd_rn(r[j], __fmul_rn(v, v));
            }
        float s01 = __fadd_rn(r[0], r[1]), s23 = __fadd_rn(r[2], r[3]);
        float s45 = __fadd_rn(r[4], r[5]), s67 = __fadd_rn(r[6], r[7]);
        b[blk] = __fadd_rn(__fadd_rn(s01, s23), __fadd_rn(s45, s67));
    }
    return __fadd_rn(__fadd_rn(b[0], b[1]), __fadd_rn(b[2], b[3]));
}

__global__ __launch_bounds__(256)
void rowsq_np(const float* __restrict__ a, float* __restrict__ out, int nrows)
{
    int r = blockIdx.x * 256 + threadIdx.x;
    if (r >= nrows) return;
    out[r] = np_pairwise_sq_512(a + (size_t)r * 512);
}

__global__ __launch_bounds__(256)
void rowsq_c(const float* __restrict__ zc, float* __restrict__ z2c,
             const int* __restrict__ cnt)
{
    int r = blockIdx.x * 256 + threadIdx.x;
    int nn = *cnt;
    nn = nn < 0 ? 0 : (nn > CAP ? CAP : nn);
    if (r >= nn) return;
    z2c[r] = np_pairwise_sq_512(zc + (size_t)r * 512);
}

// ---------- margin-gated argmin -> qb only (r18/r19/r20-proven) ----------
__global__ __launch_bounds__(256)
void argmin_margin(const float* __restrict__ s, const float* __restrict__ E,
                   short* __restrict__ qb, int* __restrict__ slist, int* __restrict__ counter)
{
    const int wave = threadIdx.x >> 6;
    const int lane = threadIdx.x & 63;
    const size_t row = (size_t)blockIdx.x * 4 + wave;
    const float* srow = s + row * 256;
    float m1 = 3.0e38f, m2 = 3.0e38f;
    int i1 = 0;
#pragma unroll
    for (int t = 0; t < 4; ++t) {
        int i = lane + t * 64;
        float v = srow[i];
        if (v < m1 || (v == m1 && i < i1)) { m2 = m1; m1 = v; i1 = i; }
        else m2 = fminf(m2, v);
    }
#pragma unroll
    for (int mm = 32; mm; mm >>= 1) {
        float o1 = __shfl_xor(m1, mm);
        int   oi = __shfl_xor(i1, mm);
        float o2 = __shfl_xor(m2, mm);
        if (o1 < m1 || (o1 == m1 && oi < i1)) { m2 = fminf(m1, o2); m1 = o1; i1 = oi; }
        else m2 = fminf(m2, o1);
    }
    if (m2 - m1 > TAU) {
        const float4* er = (const float4*)(E + (size_t)i1 * 512);
        float4 e0 = er[lane * 2], e1 = er[lane * 2 + 1];
        bf16x8 bv8;
        bv8[0] = f2bf(e0.x); bv8[1] = f2bf(e0.y); bv8[2] = f2bf(e0.z); bv8[3] = f2bf(e0.w);
        bv8[4] = f2bf(e1.x); bv8[5] = f2bf(e1.y); bv8[6] = f2bf(e1.z); bv8[7] = f2bf(e1.w);
        *(bf16x8*)&qb[row * 512 + lane * 8] = bv8;
    } else if (lane == 0) {
        int slot = atomicAdd(counter, 1);
        slist[slot] = (int)row;
    }
}

// ---------- exact argmin over compacted d2 + scatter qb (r18/r19/r20-proven) ----------
__global__ __launch_bounds__(256)
void argmin_scatter(const float* __restrict__ d2c, const float* __restrict__ E,
                    short* __restrict__ qb, const int* __restrict__ slist,
                    const int* __restrict__ cnt)
{
    const int wave = threadIdx.x >> 6;
    const int lane = threadIdx.x & 63;
    const int b = blockIdx.x * 4 + wave;
    if (b >= *cnt) return;
    const int r = slist[b];
    const float* srow = d2c + (size_t)b * 256;
    float bv = srow[lane];
    int bi = lane;
#pragma unroll
    for (int t = 1; t < 4; ++t) {
        int i = lane + t * 64;
        float v = srow[i];
        if (v < bv) { bv = v; bi = i; }
    }
#pragma unroll
    for (int m = 32; m; m >>= 1) {
        float ov = __shfl_xor(bv, m);
        int oi = __shfl_xor(bi, m);
        if (ov < bv || (ov == bv && oi < bi)) { bv = ov; bi = oi; }
    }
    const float4* er = (const float4*)(E + (size_t)bi * 512);
    float4 e0 = er[lane * 2], e1 = er[lane * 2 + 1];
    bf16x8 bv8;
    bv8[0] = f2bf(e0.x); bv8[1] = f2bf(e0.y); bv8[2] = f2bf(e0.z); bv8[3] = f2bf(e0.w);
    bv8[4] = f2bf(e1.x); bv8[5] = f2bf(e1.y); bv8[6] = f2bf(e1.z); bv8[7] = f2bf(e1.w);
    *(bf16x8*)&qb[(size_t)r * 512 + lane * 8] = bv8;
}

// ---------- loss: z f32 vs qb bf16 (r18/r19/r20-proven) ----------
__global__ __launch_bounds__(256)
void loss_partial(const float* __restrict__ z, const short* __restrict__ qb,
                  double* __restrict__ partials, long n4)
{
    const float4* z4 = (const float4*)z;
    double s = 0.0;
    for (long i = (long)blockIdx.x * 256 + threadIdx.x; i < n4; i += (long)gridDim.x * 256) {
        float4 a = z4[i];
        const unsigned short* qp = (const unsigned short*)(qb + i * 4);
        double dx = (double)a.x - (double)bf2f(qp[0]);
        double dy = (double)a.y - (double)bf2f(qp[1]);
        double dz = (double)a.z - (double)bf2f(qp[2]);
        double dw = (double)a.w - (double)bf2f(qp[3]);
        s += dx * dx + dy * dy + dz * dz + dw * dw;
    }
    __shared__ double red[256];
    red[threadIdx.x] = s;
    __syncthreads();
    for (int off = 128; off; off >>= 1) {
        if (threadIdx.x < off) red[threadIdx.x] += red[threadIdx.x + off];
        __syncthreads();
    }
    if (threadIdx.x == 0) partials[blockIdx.x] = red[0];
}

__global__ __launch_bounds__(256)
void loss_final(const double* __restrict__ partials, float* __restrict__ out)
{
    __shared__ double red[256];
    double s = 0.0;
    for (int i = threadIdx.x; i < 1024; i += 256) s += partials[i];
    red[threadIdx.x] = s;
    __syncthreads();
    for (int off = 128; off; off >>= 1) {
        if (threadIdx.x < off) red[threadIdx.x] += red[threadIdx.x + off];
        __syncthreads();
    }
    if (threadIdx.x == 0) out[0] = (float)(red[0] * (1.25 / 16777216.0));
}

// ---------- transpose f32 [K][N] -> bf16 [N][K] ----------
__global__ __launch_bounds__(256)
void transpose_bf16(const float* __restrict__ in, short* __restrict__ out,
                    int N, int kshift, long total)
{
    long i = (long)blockIdx.x * 256 + threadIdx.x;
    if (i >= total) return;
    int k = (int)(i & ((1 << kshift) - 1));
    int n = (int)(i >> kshift);
    out[i] = f2bf(in[(size_t)k * N + n]);
}

// ---------- decoder GEMM via bf16 MFMA (round-8 proven) ----------
template<bool RELU, bool OUTBF16>
__global__ __launch_bounds__(256)
void gemm_dec_bf16(const short* __restrict__ A, const short* __restrict__ Bt,
                   const float* __restrict__ bias, void* __restrict__ Cout,
                   int N, int K)
{
    __shared__ short As[128][72];
    __shared__ short Bs[128][72];
    const int tid = threadIdx.x;
    const int lane = tid & 63;
    const int wave = tid >> 6;
    const int wm = (wave >> 1) * 64;
    const int wn = (wave & 1) * 64;
    const size_t bm = (size_t)blockIdx.x * 128;
    const size_t bn = (size_t)blockIdx.y * 128;
    const int fr = lane & 15;
    const int fk8 = (lane >> 4) * 8;

    f32x4 acc[4][4];
#pragma unroll
    for (int m = 0; m < 4; ++m)
#pragma unroll
        for (int n = 0; n < 4; ++n) acc[m][n] = (f32x4)0.f;

    const int sr = tid >> 1;
    const int sk = (tid & 1) * 32;

    for (int k0 = 0; k0 < K; k0 += 64) {
        const uint4* ap4 = (const uint4*)(A + (bm + sr) * (size_t)K + k0 + sk);
        const uint4* bp4 = (const uint4*)(Bt + (bn + sr) * (size_t)K + k0 + sk);
        uint4 av[4], bv[4];
#pragma unroll
        for (int j = 0; j < 4; ++j) { av[j] = ap4[j]; bv[j] = bp4[j]; }
        __syncthreads();
#pragma unroll
        for (int j = 0; j < 4; ++j) {
            *(uint4*)&As[sr][sk + 8 * j] = av[j];
            *(uint4*)&Bs[sr][sk + 8 * j] = bv[j];
        }
        __syncthreads();
#pragma unroll
        for (int kk = 0; kk < 2; ++kk) {
            bf16x8 a[4], b[4];
#pragma unroll
            for (int m = 0; m < 4; ++m)
                a[m] = *(const bf16x8*)&As[wm + m * 16 + fr][kk * 32 + fk8];
#pragma unroll
            for (int n = 0; n < 4; ++n)
                b[n] = *(const bf16x8*)&Bs[wn + n * 16 + fr][kk * 32 + fk8];
#pragma unroll
            for (int m = 0; m < 4; ++m)
#pragma unroll
                for (int n = 0; n < 4; ++n)
                    acc[m][n] = __builtin_amdgcn_mfma_f32_16x16x32_bf16(a[m], b[n], acc[m][n], 0, 0, 0);
        }
    }
#pragma unroll
    for (int m = 0; m < 4; ++m)
#pragma unroll
        for (int n = 0; n < 4; ++n)
#pragma unroll
            for (int i = 0; i < 4; ++i) {
                const size_t row = bm + wm + m * 16 + (lane >> 4) * 4 + i;
                const int col = (int)bn + wn + n * 16 + fr;
                float v = acc[m][n][i] + bias[col];
                if (RELU) v = fmaxf(v, 0.f);
                if (OUTBF16) ((short*)Cout)[row * (size_t)N + col] = f2bf(v);
                else         ((float*)Cout)[row * (size_t)N + col] = v;
            }
}

extern "C" void kernel_launch(void* const* d_in, const int* in_sizes, int n_in,
                              void* d_out, int out_size, void* d_ws, size_t ws_size,
                              hipStream_t stream)
{
    const float* x   = (const float*)d_in[0];
    const float* W1  = (const float*)d_in[1];
    const float* b1  = (const float*)d_in[2];
    const float* W2  = (const float*)d_in[3];
    const float* b2  = (const float*)d_in[4];
    const float* E   = (const float*)d_in[5];
    const float* Wd1 = (const float*)d_in[6];
    const float* bd1 = (const float*)d_in[7];
    const float* Wd2 = (const float*)d_in[8];
    const float* bd2 = (const float*)d_in[9];
    float* out = (float*)d_out;

    float* ws = (float*)d_ws;
    float*  h    = ws;                           // fast h' [0, 33.5M); dead after GEMM2
    float*  hc   = ws;                           // [0, 8.4M) compact h (recompute)
    float*  zc   = ws + 8388608;                 // [8.4M, 12.6M)
    float*  d2c  = ws + 12582912;                // [12.6M, 14.7M)
    float*  z2c  = ws + 14680064;                // [14.7M, +8192)
    short*  a1b  = (short*)ws;                   // decoder phase
    short*  qb   = (short*)(ws + 16777216);      // bf16 q [16.8M, 33.5M)
    float*  z    = ws + 33554432;                // fast z' f32 [33.5M, 50.3M)
    // FIXED sizing: W1h/W1l each need 524,288 shorts = 262,144 floats. DISJOINT:
    short*  W1h  = (short*)(ws + 50331648);      // floats [50331648, 50593792)
    short*  W1l  = (short*)(ws + 50593792);      // floats [50593792, 50855936)
    float*  sbuf = ws + 67108864;                // s' scores [67.1M, 75.5M)
    short*  Wd1t = (short*)(ws + 67108864);      // decoder phase (sbuf dead)
    short*  Wd2t = (short*)(ws + 67108864 + 65536);
    float*  e2v  = ws + 75530240;                // 256
    double* partials = (double*)(ws + 75530496); // 1024 f64
    float*  Et   = ws + 75532544;                // 131,072
    int*    slist   = (int*)(ws + 75663616);     // 32,768
    int*    counter = (int*)(ws + 75696384);     // 1

    dim3 blk(256);
    // pre-split W1 for bf16x3 GEMM1 (buffers now disjoint)
    split_w<<<dim3(2048), blk, 0, stream>>>(W1, W1h, W1l, 512, 10, 524288L);
    transpose_f32<<<dim3(512), blk, 0, stream>>>(E, Et, counter);   // + zero counter
    rowsq_np<<<dim3(1), blk, 0, stream>>>(E, e2v, 256);
    // fast path: GEMM1 via bf16x3 MFMA; GEMM2 + s-GEMM stay proven f32t
    gemm_bf3g1<<<dim3(512, 4), blk, 0, stream>>>(x, W1h, W1l, b1, h, 1024, 512, 1024);
    gemm_f32t<0><<<dim3(512, 2), blk, 0, stream>>>(h, W2, b2, z, 512, 256, 256, 512);
    gemm_f32t<1><<<dim3(256, 2), blk, 0, stream>>>(z, Et, e2v, sbuf, 512, 256, 256, 512);
    // margin-gated argmin (TAU=2e-4, proven gating config)
    argmin_margin<<<dim3(8192), blk, 0, stream>>>(sbuf, E, qb, slist, counter);
    // bit-exact recompute, single-shot indirect (r20-proven)
    gemm_f64<true ><<<dim3(128, 8), blk, 0, stream>>>(x,  W1, b1, nullptr, hc, 1024, 512, 512, 1024, counter, 2, slist);
    gemm_f64<false><<<dim3(128, 4), blk, 0, stream>>>(hc, W2, b2, nullptr, zc,  512, 256, 256,  512, counter, 2, nullptr);
    rowsq_c<<<dim3(32), blk, 0, stream>>>(zc, z2c, counter);
    gemm_f64<false><<<dim3(64, 4), blk, 0, stream>>>(zc, Et, z2c, e2v, d2c, 512, 256, 256, 512, counter, 1, nullptr);
    argmin_scatter<<<dim3(2048), blk, 0, stream>>>(d2c, E, qb, slist, counter);
    // vq_loss = 1.25 * mean((qb - z)^2)
    loss_partial<<<dim3(1024), blk, 0, stream>>>(z, qb, partials, 4194304L);
    loss_final<<<dim3(1), blk, 0, stream>>>(partials, out + (size_t)out_size - 1);
    // decoder weights (sbuf dead)
    transpose_bf16<<<dim3(512), blk, 0, stream>>>(Wd1, Wd1t, 512, 8, 131072L);
    transpose_bf16<<<dim3(2048), blk, 0, stream>>>(Wd2, Wd2t, 1024, 9, 524288L);
    // decoder (bf16 MFMA; zq == q in forward)
    gemm_dec_bf16<true,  true ><<<dim3(512, 4), blk, 0, stream>>>(qb,  Wd1t, bd1, a1b, 512, 256);
    gemm_dec_bf16<false, false><<<dim3(512, 8), blk, 0, stream>>>(a1b, Wd2t, bd2, out, 1024, 512);
}